// Round 1
// baseline (1871.452 us; speedup 1.0000x reference)
//
#include <hip/hip_runtime.h>
#include <math.h>

#define BB  2
#define SS  2048
#define DD  1024
#define HH  16
#define DHH 64
#define MM  (BB * SS)   // 4096 rows

// ---------------------------------------------------------------------------
// Generic fp32 GEMM:  C[M,N] = (A[M,K] @ W[K,N] + bias[N]) * scale (+ res[M,N]) (ReLU?)
// 64x64 tile, BK=16, 256 threads, 4x4 micro-tile per thread.
// ---------------------------------------------------------------------------
template <int RELU>
__global__ __launch_bounds__(256)
void gemm_kernel(const float* __restrict__ A, const float* __restrict__ W,
                 const float* __restrict__ bias, const float* __restrict__ res,
                 float* __restrict__ C, int M, int N, int K, float scale)
{
    __shared__ float As[16][65];   // [k][m], padded
    __shared__ float Bs[16][64];   // [k][n]

    const int tid = threadIdx.x;
    const int tx = tid & 15;        // 0..15 -> n group
    const int ty = tid >> 4;        // 0..15 -> m group
    const int bm = blockIdx.y * 64;
    const int bn = blockIdx.x * 64;

    const int kk_a = tid & 15;      // A-load: k within tile
    const int mm_a = tid >> 4;      // A-load: m base
    const int nn_b = tid & 63;      // B-load: n within tile
    const int kk_b = tid >> 6;      // B-load: k base (0..3)

    float acc[4][4] = {};

    for (int k0 = 0; k0 < K; k0 += 16) {
#pragma unroll
        for (int r = 0; r < 4; ++r)
            As[kk_a][mm_a + 16 * r] =
                A[(size_t)(bm + mm_a + 16 * r) * K + (k0 + kk_a)];
#pragma unroll
        for (int r = 0; r < 4; ++r)
            Bs[kk_b + 4 * r][nn_b] =
                W[(size_t)(k0 + kk_b + 4 * r) * N + (bn + nn_b)];
        __syncthreads();

#pragma unroll
        for (int kk = 0; kk < 16; ++kk) {
            float a[4];
#pragma unroll
            for (int i = 0; i < 4; ++i) a[i] = As[kk][ty * 4 + i];
            const float4 bv = *reinterpret_cast<const float4*>(&Bs[kk][tx * 4]);
            const float b[4] = {bv.x, bv.y, bv.z, bv.w};
#pragma unroll
            for (int i = 0; i < 4; ++i)
#pragma unroll
                for (int j = 0; j < 4; ++j)
                    acc[i][j] += a[i] * b[j];
        }
        __syncthreads();
    }

#pragma unroll
    for (int i = 0; i < 4; ++i) {
        const int m = bm + ty * 4 + i;
        float vv[4];
#pragma unroll
        for (int j = 0; j < 4; ++j) {
            const int n = bn + tx * 4 + j;
            float val = (acc[i][j] + bias[n]) * scale;
            if (res) val += res[(size_t)m * N + n];
            if (RELU) val = fmaxf(val, 0.0f);
            vv[j] = val;
        }
        *reinterpret_cast<float4*>(&C[(size_t)m * N + bn + tx * 4]) =
            make_float4(vv[0], vv[1], vv[2], vv[3]);
    }
}

// ---------------------------------------------------------------------------
// Flash attention (fp32): one block per (q-tile of 64, head, batch).
// q already pre-scaled by 1/sqrt(DH). Layouts are [B,S,H,DH].
// Online softmax state (m,l) replicated across the 16 lanes of each row group.
// ---------------------------------------------------------------------------
__global__ __launch_bounds__(256)
void attn_kernel(const float* __restrict__ q, const float* __restrict__ k,
                 const float* __restrict__ v, const int* __restrict__ mask,
                 float* __restrict__ o)
{
    const int b  = blockIdx.z;
    const int h  = blockIdx.y;
    const int q0 = blockIdx.x * 64;

    __shared__ float Qs[64][65];
    __shared__ float Ks[64][65];
    __shared__ float Vs[64][65];
    __shared__ float Ps[64][65];
    __shared__ float maskadd[64];

    const int tid = threadIdx.x;
    const int tx = tid & 15, ty = tid >> 4;
    const int d  = tid & 63;        // loader: element within row
    const int r0 = tid >> 6;        // loader: row base (0..3)

    // load Q tile
#pragma unroll
    for (int rr = 0; rr < 16; ++rr) {
        const int r = r0 + 4 * rr;
        Qs[r][d] = q[((size_t)(b * SS + q0 + r) * HH + h) * DHH + d];
    }

    float accO[4][4] = {};
    float mrow[4], lrow[4];
#pragma unroll
    for (int i = 0; i < 4; ++i) { mrow[i] = -INFINITY; lrow[i] = 0.0f; }

    for (int kt = 0; kt < SS / 64; ++kt) {
        const int k0 = kt * 64;
        __syncthreads();   // prev iter done with Ks/Vs/Ps; Qs visible (iter 0)
#pragma unroll
        for (int rr = 0; rr < 16; ++rr) {
            const int r = r0 + 4 * rr;
            Ks[r][d] = k[((size_t)(b * SS + k0 + r) * HH + h) * DHH + d];
            Vs[r][d] = v[((size_t)(b * SS + k0 + r) * HH + h) * DHH + d];
        }
        if (tid < 64) maskadd[tid] = mask[b * SS + k0 + tid] ? 0.0f : -1e9f;
        __syncthreads();

        // S tile: sv[i][j] = Q[ty*4+i] . K[tx*4+j]
        float sv[4][4] = {};
#pragma unroll 8
        for (int dd = 0; dd < 64; ++dd) {
            float a[4], bb[4];
#pragma unroll
            for (int i = 0; i < 4; ++i) a[i]  = Qs[ty * 4 + i][dd];
#pragma unroll
            for (int j = 0; j < 4; ++j) bb[j] = Ks[tx * 4 + j][dd];
#pragma unroll
            for (int i = 0; i < 4; ++i)
#pragma unroll
                for (int j = 0; j < 4; ++j)
                    sv[i][j] += a[i] * bb[j];
        }
        float madd[4];
#pragma unroll
        for (int j = 0; j < 4; ++j) madd[j] = maskadd[tx * 4 + j];
#pragma unroll
        for (int i = 0; i < 4; ++i)
#pragma unroll
            for (int j = 0; j < 4; ++j) sv[i][j] += madd[j];

        // online softmax per row (reduce across the 16 lanes sharing ty)
#pragma unroll
        for (int i = 0; i < 4; ++i) {
            float mx = fmaxf(fmaxf(sv[i][0], sv[i][1]), fmaxf(sv[i][2], sv[i][3]));
#pragma unroll
            for (int off = 1; off < 16; off <<= 1)
                mx = fmaxf(mx, __shfl_xor(mx, off));
            const float mnew = fmaxf(mrow[i], mx);
            const float corr = __expf(mrow[i] - mnew);
            float psum = 0.0f;
#pragma unroll
            for (int j = 0; j < 4; ++j) {
                const float p = __expf(sv[i][j] - mnew);
                Ps[ty * 4 + i][tx * 4 + j] = p;
                psum += p;
            }
#pragma unroll
            for (int off = 1; off < 16; off <<= 1)
                psum += __shfl_xor(psum, off);
            lrow[i] = lrow[i] * corr + psum;
            mrow[i] = mnew;
#pragma unroll
            for (int j = 0; j < 4; ++j) accO[i][j] *= corr;
        }
        __syncthreads();   // Ps visible

        // accO += P @ V
#pragma unroll 8
        for (int kk = 0; kk < 64; ++kk) {
            float a[4], bb[4];
#pragma unroll
            for (int i = 0; i < 4; ++i) a[i]  = Ps[ty * 4 + i][kk];
#pragma unroll
            for (int j = 0; j < 4; ++j) bb[j] = Vs[kk][tx * 4 + j];
#pragma unroll
            for (int i = 0; i < 4; ++i)
#pragma unroll
                for (int j = 0; j < 4; ++j)
                    accO[i][j] += a[i] * bb[j];
        }
    }

#pragma unroll
    for (int i = 0; i < 4; ++i) {
        const float inv = 1.0f / lrow[i];
        const int s = q0 + ty * 4 + i;
#pragma unroll
        for (int j = 0; j < 4; ++j)
            o[((size_t)(b * SS + s) * HH + h) * DHH + tx * 4 + j] = accO[i][j] * inv;
    }
}

// ---------------------------------------------------------------------------
// LayerNorm over D=1024: one block (256 thr) per row, float4 per thread.
// ---------------------------------------------------------------------------
__global__ __launch_bounds__(256)
void ln_kernel(const float* __restrict__ x, const float* __restrict__ g,
               const float* __restrict__ beta, float* __restrict__ out)
{
    const int row = blockIdx.x;
    const int tid = threadIdx.x;
    const float4 xl = reinterpret_cast<const float4*>(x + (size_t)row * DD)[tid];
    float s  = xl.x + xl.y + xl.z + xl.w;
    float sq = xl.x * xl.x + xl.y * xl.y + xl.z * xl.z + xl.w * xl.w;
#pragma unroll
    for (int off = 1; off < 64; off <<= 1) {
        s  += __shfl_xor(s, off);
        sq += __shfl_xor(sq, off);
    }
    __shared__ float ssum[4], ssq[4];
    const int wid = tid >> 6;
    if ((tid & 63) == 0) { ssum[wid] = s; ssq[wid] = sq; }
    __syncthreads();
    s  = ssum[0] + ssum[1] + ssum[2] + ssum[3];
    sq = ssq[0]  + ssq[1]  + ssq[2]  + ssq[3];
    const float mean = s * (1.0f / DD);
    const float var  = fmaxf(sq * (1.0f / DD) - mean * mean, 0.0f);
    const float rstd = rsqrtf(var + 1e-5f);
    const float4 gv = reinterpret_cast<const float4*>(g)[tid];
    const float4 bv = reinterpret_cast<const float4*>(beta)[tid];
    float4 ov;
    ov.x = (xl.x - mean) * rstd * gv.x + bv.x;
    ov.y = (xl.y - mean) * rstd * gv.y + bv.y;
    ov.z = (xl.z - mean) * rstd * gv.z + bv.z;
    ov.w = (xl.w - mean) * rstd * gv.w + bv.w;
    reinterpret_cast<float4*>(out + (size_t)row * DD)[tid] = ov;
}

// ---------------------------------------------------------------------------
extern "C" void kernel_launch(void* const* d_in, const int* in_sizes, int n_in,
                              void* d_out, int out_size, void* d_ws, size_t ws_size,
                              hipStream_t stream)
{
    (void)in_sizes; (void)n_in; (void)out_size; (void)ws_size;

    const float* x     = (const float*)d_in[0];
    const int*   mask  = (const int*)  d_in[1];
    const float* wq    = (const float*)d_in[2];
    const float* bq    = (const float*)d_in[3];
    const float* wk    = (const float*)d_in[4];
    const float* bk    = (const float*)d_in[5];
    const float* wv    = (const float*)d_in[6];
    const float* bv    = (const float*)d_in[7];
    const float* wo    = (const float*)d_in[8];
    const float* bo    = (const float*)d_in[9];
    const float* ln1_g = (const float*)d_in[10];
    const float* ln1_b = (const float*)d_in[11];
    const float* w1    = (const float*)d_in[12];
    const float* b1    = (const float*)d_in[13];
    const float* w2    = (const float*)d_in[14];
    const float* b2    = (const float*)d_in[15];
    const float* ln2_g = (const float*)d_in[16];
    const float* ln2_b = (const float*)d_in[17];

    float* out = (float*)d_out;
    float* ws  = (float*)d_ws;

    const size_t R = (size_t)MM * DD;   // 4M floats per [4096,1024] buffer
    float* qb   = ws;           // region 0
    float* kb   = ws + R;       // region 1
    float* vb   = ws + 2 * R;   // region 2
    float* ab   = ws + 3 * R;   // region 3
    float* t0   = qb;           // reuse 0 (q dead after attention)
    float* hb   = kb;           // reuse 1 (k dead)
    float* f1   = vb;           // reuse 2+3 as contiguous [4096,2048]
    float* t1   = qb;           // reuse 0 (t0 dead after ln1)

    const dim3 blk(256);
    const float qscale = 0.125f;   // 1/sqrt(DH=64)

    // QKV projections (scale folded into q)
    gemm_kernel<0><<<dim3(16, 64), blk, 0, stream>>>(x, wq, bq, nullptr, qb, MM, DD, DD, qscale);
    gemm_kernel<0><<<dim3(16, 64), blk, 0, stream>>>(x, wk, bk, nullptr, kb, MM, DD, DD, 1.0f);
    gemm_kernel<0><<<dim3(16, 64), blk, 0, stream>>>(x, wv, bv, nullptr, vb, MM, DD, DD, 1.0f);

    // flash attention
    attn_kernel<<<dim3(SS / 64, HH, BB), blk, 0, stream>>>(qb, kb, vb, mask, ab);

    // output projection + residual x
    gemm_kernel<0><<<dim3(16, 64), blk, 0, stream>>>(ab, wo, bo, x, t0, MM, DD, DD, 1.0f);

    // LN1
    ln_kernel<<<dim3(MM), blk, 0, stream>>>(t0, ln1_g, ln1_b, hb);

    // FFN
    gemm_kernel<1><<<dim3(32, 64), blk, 0, stream>>>(hb, w1, b1, nullptr, f1, MM, 2 * DD, DD, 1.0f);
    gemm_kernel<0><<<dim3(16, 64), blk, 0, stream>>>(f1, w2, b2, hb, t1, MM, DD, 2 * DD, 1.0f);

    // LN2 -> output
    ln_kernel<<<dim3(MM), blk, 0, stream>>>(t1, ln2_g, ln2_b, out);
}

// Round 2
// 947.434 us; speedup vs baseline: 1.9753x; 1.9753x over previous
//
#include <hip/hip_runtime.h>
#include <math.h>

#define BB  2
#define SS  2048
#define DD  1024
#define HH  16
#define DHH 64
#define MM  (BB * SS)   // 4096 rows

typedef float f32x4 __attribute__((ext_vector_type(4)));
typedef short s16x8 __attribute__((ext_vector_type(8)));

__device__ __forceinline__ unsigned short f2b(float f) {
    union { float f; unsigned u; } v; v.f = f;
    unsigned r = v.u + 0x7fffu + ((v.u >> 16) & 1u);
    return (unsigned short)(r >> 16);
}
__device__ __forceinline__ float b2f(unsigned short u) {
    union { unsigned u; float f; } v; v.u = ((unsigned)u) << 16;
    return v.f;
}

typedef __attribute__((address_space(1))) void gv_t;
typedef __attribute__((address_space(3))) void lv_t;
__device__ __forceinline__ void gld16(const void* g, void* l) {
    __builtin_amdgcn_global_load_lds((gv_t*)(void*)g, (lv_t*)l, 16, 0, 0);
}

// ---------------------------------------------------------------------------
// bf16 MFMA GEMM (m97 structure): C[M,N] = A[M,K] @ B^T[N,K] + bias (+res)(relu)
// 128x128 tile, BK=64, 256 threads (4 waves), wave -> 64x64 subtile (4x4 frags
// of 16x16x32). LDS linear [row][64], staged via global_load_lds width 16.
// RES: 0 none, 1 fp32, 2 bf16.  OUTF: 1 fp32 out, 0 bf16 out.
// ---------------------------------------------------------------------------
template <int RELU, int RES, int OUTF>
__global__ __launch_bounds__(256)
void mgemm(const unsigned short* __restrict__ A, const unsigned short* __restrict__ B,
           const float* __restrict__ bias, const void* __restrict__ res,
           void* __restrict__ out, int M, int N, int K)
{
    __shared__ short As[128 * 64];
    __shared__ short Bs[128 * 64];

    const int tid  = threadIdx.x;
    const int wave = tid >> 6, lane = tid & 63;
    const int bm = blockIdx.y * 128, bn = blockIdx.x * 128;
    const int srow = tid >> 3;           // 0..31 staging row
    const int scol = (tid & 7) * 8;      // staging k-offset (8 bf16 = 16B)
    const int wr = wave >> 1, wc = wave & 1;
    const int fr = lane & 15;            // fragment row (m or n)
    const int fk = (lane >> 4) * 8;      // fragment k-offset

    f32x4 acc[4][4];
#pragma unroll
    for (int i = 0; i < 4; ++i)
#pragma unroll
        for (int j = 0; j < 4; ++j) acc[i][j] = (f32x4){0.f, 0.f, 0.f, 0.f};

    for (int k0 = 0; k0 < K; k0 += 64) {
#pragma unroll
        for (int it = 0; it < 4; ++it) {
            gld16(&A[(size_t)(bm + it * 32 + srow) * K + k0 + scol],
                  &As[it * 2048 + wave * 512]);
            gld16(&B[(size_t)(bn + it * 32 + srow) * K + k0 + scol],
                  &Bs[it * 2048 + wave * 512]);
        }
        __syncthreads();   // compiler drains vmcnt(0) before barrier

#pragma unroll
        for (int kk = 0; kk < 2; ++kk) {
            s16x8 af[4], bf[4];
#pragma unroll
            for (int i = 0; i < 4; ++i)
                af[i] = *(const s16x8*)&As[(wr * 64 + i * 16 + fr) * 64 + kk * 32 + fk];
#pragma unroll
            for (int j = 0; j < 4; ++j)
                bf[j] = *(const s16x8*)&Bs[(wc * 64 + j * 16 + fr) * 64 + kk * 32 + fk];
#pragma unroll
            for (int i = 0; i < 4; ++i)
#pragma unroll
                for (int j = 0; j < 4; ++j)
                    acc[i][j] = __builtin_amdgcn_mfma_f32_16x16x32_bf16(
                        af[i], bf[j], acc[i][j], 0, 0, 0);
        }
        __syncthreads();
    }

    // epilogue: C/D layout col=lane&15, row=(lane>>4)*4+reg (m89-verified)
    const int r0 = bm + wr * 64 + (lane >> 4) * 4;
    const int c0 = bn + wc * 64 + (lane & 15);
    const float* resf          = (const float*)res;
    const unsigned short* resh = (const unsigned short*)res;
    float* outf          = (float*)out;
    unsigned short* outh = (unsigned short*)out;
#pragma unroll
    for (int i = 0; i < 4; ++i)
#pragma unroll
        for (int j = 0; j < 4; ++j) {
            const int col = c0 + j * 16;
            const float bcol = bias[col];
#pragma unroll
            for (int r = 0; r < 4; ++r) {
                const int row = r0 + i * 16 + r;
                float v = acc[i][j][r] + bcol;
                if (RES == 1) v += resf[(size_t)row * N + col];
                if (RES == 2) v += b2f(resh[(size_t)row * N + col]);
                if (RELU)     v = fmaxf(v, 0.f);
                if (OUTF) outf[(size_t)row * N + col] = v;
                else      outh[(size_t)row * N + col] = f2b(v);
            }
        }
}

// ---------------------------------------------------------------------------
// fp32 [K][N] -> bf16 [N][K] transpose (64x64 LDS tile)
// ---------------------------------------------------------------------------
__global__ __launch_bounds__(256)
void tpose(const float* __restrict__ in, unsigned short* __restrict__ out, int K, int N)
{
    __shared__ float T[64][65];
    const int tid = threadIdx.x;
    const int k0 = blockIdx.y * 64, n0 = blockIdx.x * 64;
    const int c = tid & 63, rb = tid >> 6;
#pragma unroll
    for (int it = 0; it < 16; ++it) {
        const int r = it * 4 + rb;
        T[r][c] = in[(size_t)(k0 + r) * N + n0 + c];
    }
    __syncthreads();
#pragma unroll
    for (int it = 0; it < 16; ++it) {
        const int r = it * 4 + rb;
        out[(size_t)(n0 + r) * K + k0 + c] = f2b(T[c][r]);
    }
}

__global__ __launch_bounds__(256)
void cvt_bf16(const float* __restrict__ in, unsigned short* __restrict__ out, int n4)
{
    const int i = blockIdx.x * 256 + threadIdx.x;
    if (i >= n4) return;
    const float4 v = ((const float4*)in)[i];
    ushort4 o;
    o.x = f2b(v.x); o.y = f2b(v.y); o.z = f2b(v.z); o.w = f2b(v.w);
    ((ushort4*)out)[i] = o;
}

__global__ __launch_bounds__(256)
void pack_bias(const float* __restrict__ bq, const float* __restrict__ bk,
               const float* __restrict__ bv, float* __restrict__ o)
{
    const int i = blockIdx.x * 256 + threadIdx.x;
    if (i < 1024) o[i] = bq[i];
    else if (i < 2048) o[i] = bk[i - 1024];
    else if (i < 3072) o[i] = bv[i - 2048];
}

// ---------------------------------------------------------------------------
// Flash attention (fp32 math, bf16 in/out). qkv: [B*S][3072] = [q|k|v] rows.
// One block per (q-tile 64, head, batch). Q scaled by 1/8 at load.
// ---------------------------------------------------------------------------
__global__ __launch_bounds__(256)
void attn_kernel(const unsigned short* __restrict__ qkv, const int* __restrict__ mask,
                 unsigned short* __restrict__ o)
{
    const int b  = blockIdx.z;
    const int h  = blockIdx.y;
    const int q0 = blockIdx.x * 64;

    __shared__ float Qs[64][65];
    __shared__ float Ks[64][65];
    __shared__ float Vs[64][65];
    __shared__ float Ps[64][65];
    __shared__ float maskadd[64];

    const int tid = threadIdx.x;
    const int tx = tid & 15, ty = tid >> 4;
    const int d  = tid & 63;
    const int r0 = tid >> 6;

#pragma unroll
    for (int rr = 0; rr < 16; ++rr) {
        const int r = r0 + 4 * rr;
        Qs[r][d] = 0.125f * b2f(qkv[(size_t)(b * SS + q0 + r) * 3072 + h * DHH + d]);
    }

    float accO[4][4] = {};
    float mrow[4], lrow[4];
#pragma unroll
    for (int i = 0; i < 4; ++i) { mrow[i] = -INFINITY; lrow[i] = 0.0f; }

    for (int kt = 0; kt < SS / 64; ++kt) {
        const int k0 = kt * 64;
        __syncthreads();
#pragma unroll
        for (int rr = 0; rr < 16; ++rr) {
            const int r = r0 + 4 * rr;
            Ks[r][d] = b2f(qkv[(size_t)(b * SS + k0 + r) * 3072 + 1024 + h * DHH + d]);
            Vs[r][d] = b2f(qkv[(size_t)(b * SS + k0 + r) * 3072 + 2048 + h * DHH + d]);
        }
        if (tid < 64) maskadd[tid] = mask[b * SS + k0 + tid] ? 0.0f : -1e9f;
        __syncthreads();

        float sv[4][4] = {};
#pragma unroll 8
        for (int dd = 0; dd < 64; ++dd) {
            float a[4], bbv[4];
#pragma unroll
            for (int i = 0; i < 4; ++i) a[i]   = Qs[ty * 4 + i][dd];
#pragma unroll
            for (int j = 0; j < 4; ++j) bbv[j] = Ks[tx * 4 + j][dd];
#pragma unroll
            for (int i = 0; i < 4; ++i)
#pragma unroll
                for (int j = 0; j < 4; ++j)
                    sv[i][j] += a[i] * bbv[j];
        }
        float madd[4];
#pragma unroll
        for (int j = 0; j < 4; ++j) madd[j] = maskadd[tx * 4 + j];
#pragma unroll
        for (int i = 0; i < 4; ++i)
#pragma unroll
            for (int j = 0; j < 4; ++j) sv[i][j] += madd[j];

#pragma unroll
        for (int i = 0; i < 4; ++i) {
            float mx = fmaxf(fmaxf(sv[i][0], sv[i][1]), fmaxf(sv[i][2], sv[i][3]));
#pragma unroll
            for (int off = 1; off < 16; off <<= 1)
                mx = fmaxf(mx, __shfl_xor(mx, off));
            const float mnew = fmaxf(mrow[i], mx);
            const float corr = __expf(mrow[i] - mnew);
            float psum = 0.0f;
#pragma unroll
            for (int j = 0; j < 4; ++j) {
                const float p = __expf(sv[i][j] - mnew);
                Ps[ty * 4 + i][tx * 4 + j] = p;
                psum += p;
            }
#pragma unroll
            for (int off = 1; off < 16; off <<= 1)
                psum += __shfl_xor(psum, off);
            lrow[i] = lrow[i] * corr + psum;
            mrow[i] = mnew;
#pragma unroll
            for (int j = 0; j < 4; ++j) accO[i][j] *= corr;
        }
        __syncthreads();

#pragma unroll 8
        for (int kk = 0; kk < 64; ++kk) {
            float a[4], bbv[4];
#pragma unroll
            for (int i = 0; i < 4; ++i) a[i]   = Ps[ty * 4 + i][kk];
#pragma unroll
            for (int j = 0; j < 4; ++j) bbv[j] = Vs[kk][tx * 4 + j];
#pragma unroll
            for (int i = 0; i < 4; ++i)
#pragma unroll
                for (int j = 0; j < 4; ++j)
                    accO[i][j] += a[i] * bbv[j];
        }
    }

#pragma unroll
    for (int i = 0; i < 4; ++i) {
        const float inv = 1.0f / lrow[i];
        const int s = q0 + ty * 4 + i;
#pragma unroll
        for (int j = 0; j < 4; ++j)
            o[(size_t)(b * SS + s) * DD + h * DHH + tx * 4 + j] = f2b(accO[i][j] * inv);
    }
}

// ---------------------------------------------------------------------------
// LayerNorm D=1024. OUTBF: 1 -> bf16 out, 0 -> fp32 out.
// ---------------------------------------------------------------------------
template <int OUTBF>
__global__ __launch_bounds__(256)
void ln_kernel(const float* __restrict__ x, const float* __restrict__ g,
               const float* __restrict__ beta, void* __restrict__ outv)
{
    const int row = blockIdx.x;
    const int tid = threadIdx.x;
    const float4 xl = reinterpret_cast<const float4*>(x + (size_t)row * DD)[tid];
    float s  = xl.x + xl.y + xl.z + xl.w;
    float sq = xl.x * xl.x + xl.y * xl.y + xl.z * xl.z + xl.w * xl.w;
#pragma unroll
    for (int off = 1; off < 64; off <<= 1) {
        s  += __shfl_xor(s, off);
        sq += __shfl_xor(sq, off);
    }
    __shared__ float ssum[4], ssq[4];
    const int wid = tid >> 6;
    if ((tid & 63) == 0) { ssum[wid] = s; ssq[wid] = sq; }
    __syncthreads();
    s  = ssum[0] + ssum[1] + ssum[2] + ssum[3];
    sq = ssq[0]  + ssq[1]  + ssq[2]  + ssq[3];
    const float mean = s * (1.0f / DD);
    const float var  = fmaxf(sq * (1.0f / DD) - mean * mean, 0.0f);
    const float rstd = rsqrtf(var + 1e-5f);
    const float4 gv = reinterpret_cast<const float4*>(g)[tid];
    const float4 bv = reinterpret_cast<const float4*>(beta)[tid];
    float4 ov;
    ov.x = (xl.x - mean) * rstd * gv.x + bv.x;
    ov.y = (xl.y - mean) * rstd * gv.y + bv.y;
    ov.z = (xl.z - mean) * rstd * gv.z + bv.z;
    ov.w = (xl.w - mean) * rstd * gv.w + bv.w;
    if (OUTBF) {
        ushort4 o4;
        o4.x = f2b(ov.x); o4.y = f2b(ov.y); o4.z = f2b(ov.z); o4.w = f2b(ov.w);
        reinterpret_cast<ushort4*>(outv)[(size_t)row * 256 + tid] = o4;
    } else {
        reinterpret_cast<float4*>(outv)[(size_t)row * 256 + tid] = ov;
    }
}

// ---------------------------------------------------------------------------
extern "C" void kernel_launch(void* const* d_in, const int* in_sizes, int n_in,
                              void* d_out, int out_size, void* d_ws, size_t ws_size,
                              hipStream_t stream)
{
    (void)in_sizes; (void)n_in; (void)out_size; (void)ws_size;

    const float* x     = (const float*)d_in[0];
    const int*   mask  = (const int*)  d_in[1];
    const float* wq    = (const float*)d_in[2];
    const float* bq    = (const float*)d_in[3];
    const float* wk    = (const float*)d_in[4];
    const float* bk    = (const float*)d_in[5];
    const float* wv    = (const float*)d_in[6];
    const float* bv    = (const float*)d_in[7];
    const float* wo    = (const float*)d_in[8];
    const float* bo    = (const float*)d_in[9];
    const float* ln1_g = (const float*)d_in[10];
    const float* ln1_b = (const float*)d_in[11];
    const float* w1    = (const float*)d_in[12];
    const float* b1    = (const float*)d_in[13];
    const float* w2    = (const float*)d_in[14];
    const float* b2    = (const float*)d_in[15];
    const float* ln2_g = (const float*)d_in[16];
    const float* ln2_b = (const float*)d_in[17];

    float* out = (float*)d_out;
    char*  wsb = (char*)d_ws;
    const size_t MB = 1u << 20;

    // weights (live whole launch): 0..16.02 MB
    unsigned short* wqkvT = (unsigned short*)(wsb + 0);        // [3072][1024]
    unsigned short* woT   = (unsigned short*)(wsb + 6 * MB);   // [1024][1024]
    unsigned short* w1T   = (unsigned short*)(wsb + 8 * MB);   // [2048][1024]
    unsigned short* w2T   = (unsigned short*)(wsb + 12 * MB);  // [1024][2048]
    float*          bqkv  = (float*)(wsb + 16 * MB);           // [3072]
    // activations (region-reused; peak 57 MB)
    unsigned short* qkvb  = (unsigned short*)(wsb + 17 * MB);  // [4096][3072] bf16 (17..41)
    unsigned short* xb    = (unsigned short*)(wsb + 41 * MB);  // [4096][1024] bf16 (41..49)
    unsigned short* ab16  = xb;                                // attn out, reuses xb
    float*          t0    = (float*)(wsb + 17 * MB);           // (17..33), qkv dead
    unsigned short* hb16  = (unsigned short*)(wsb + 33 * MB);  // (33..41)
    unsigned short* f1b   = (unsigned short*)(wsb + 41 * MB);  // [4096][2048] (41..57)
    float*          t1    = (float*)(wsb + 17 * MB);           // (17..33), t0 dead

    // ---- weight prep (bf16 + transpose to [N][K]) ----
    cvt_bf16<<<4096, 256, 0, stream>>>(x, xb, MM * DD / 4);
    tpose<<<dim3(16, 16), 256, 0, stream>>>(wq, wqkvT, DD, DD);
    tpose<<<dim3(16, 16), 256, 0, stream>>>(wk, wqkvT + 1024 * 1024, DD, DD);
    tpose<<<dim3(16, 16), 256, 0, stream>>>(wv, wqkvT + 2 * 1024 * 1024, DD, DD);
    tpose<<<dim3(16, 16), 256, 0, stream>>>(wo, woT, DD, DD);
    tpose<<<dim3(32, 16), 256, 0, stream>>>(w1, w1T, DD, 2 * DD);
    tpose<<<dim3(16, 32), 256, 0, stream>>>(w2, w2T, 2 * DD, DD);
    pack_bias<<<12, 256, 0, stream>>>(bq, bk, bv, bqkv);

    // ---- fused QKV projection: [4096][3072] bf16 ----
    mgemm<0, 0, 0><<<dim3(24, 32), 256, 0, stream>>>(xb, wqkvT, bqkv, nullptr, qkvb,
                                                     MM, 3 * DD, DD);
    // ---- flash attention ----
    attn_kernel<<<dim3(SS / 64, HH, BB), 256, 0, stream>>>(qkvb, mask, ab16);
    // ---- output projection + residual x ----
    mgemm<0, 1, 1><<<dim3(8, 32), 256, 0, stream>>>(ab16, woT, bo, x, t0, MM, DD, DD);
    // ---- LN1 -> bf16 ----
    ln_kernel<1><<<MM, 256, 0, stream>>>(t0, ln1_g, ln1_b, hb16);
    // ---- FFN ----
    mgemm<1, 0, 0><<<dim3(16, 32), 256, 0, stream>>>(hb16, w1T, b1, nullptr, f1b,
                                                     MM, 2 * DD, DD);
    mgemm<0, 2, 1><<<dim3(8, 32), 256, 0, stream>>>(f1b, w2T, b2, hb16, t1,
                                                    MM, DD, 2 * DD);
    // ---- LN2 -> out ----
    ln_kernel<0><<<MM, 256, 0, stream>>>(t1, ln2_g, ln2_b, out);
}

// Round 3
// 331.711 us; speedup vs baseline: 5.6418x; 2.8562x over previous
//
#include <hip/hip_runtime.h>
#include <math.h>

#define BB  2
#define SS  2048
#define DD  1024
#define HH  16
#define DHH 64
#define MM  (BB * SS)   // 4096 rows

typedef float f32x4 __attribute__((ext_vector_type(4)));
typedef short s16x8 __attribute__((ext_vector_type(8)));

__device__ __forceinline__ unsigned short f2b(float f) {
    union { float f; unsigned u; } v; v.f = f;
    unsigned r = v.u + 0x7fffu + ((v.u >> 16) & 1u);
    return (unsigned short)(r >> 16);
}
__device__ __forceinline__ float b2f(unsigned short u) {
    union { unsigned u; float f; } v; v.u = ((unsigned)u) << 16;
    return v.f;
}

typedef __attribute__((address_space(1))) void gv_t;
typedef __attribute__((address_space(3))) void lv_t;
__device__ __forceinline__ void gld16(const void* g, void* l) {
    __builtin_amdgcn_global_load_lds((gv_t*)(void*)g, (lv_t*)l, 16, 0, 0);
}

// LDS swizzle for 64-col bf16 tiles: element index with XOR of
// sigma(row) = (row + row>>3) & 7 on the 16B-block bits (bits 3..5 of col).
__device__ __forceinline__ int sidx(int row, int col) {
    return row * 64 + (col ^ (((row + (row >> 3)) & 7) << 3));
}

// ---------------------------------------------------------------------------
// bf16 MFMA GEMM (m97 structure): C[M,N] = A[M,K] @ B^T[N,K] + bias (+res)(relu)
// ---------------------------------------------------------------------------
template <int RELU, int RES, int OUTF>
__global__ __launch_bounds__(256)
void mgemm(const unsigned short* __restrict__ A, const unsigned short* __restrict__ B,
           const float* __restrict__ bias, const void* __restrict__ res,
           void* __restrict__ out, int M, int N, int K)
{
    __shared__ short As[128 * 64];
    __shared__ short Bs[128 * 64];

    const int tid  = threadIdx.x;
    const int wave = tid >> 6, lane = tid & 63;
    const int bm = blockIdx.y * 128, bn = blockIdx.x * 128;
    const int srow = tid >> 3;
    const int scol = (tid & 7) * 8;
    const int wr = wave >> 1, wc = wave & 1;
    const int fr = lane & 15;
    const int fk = (lane >> 4) * 8;

    f32x4 acc[4][4];
#pragma unroll
    for (int i = 0; i < 4; ++i)
#pragma unroll
        for (int j = 0; j < 4; ++j) acc[i][j] = (f32x4){0.f, 0.f, 0.f, 0.f};

    for (int k0 = 0; k0 < K; k0 += 64) {
#pragma unroll
        for (int it = 0; it < 4; ++it) {
            gld16(&A[(size_t)(bm + it * 32 + srow) * K + k0 + scol],
                  &As[it * 2048 + wave * 512]);
            gld16(&B[(size_t)(bn + it * 32 + srow) * K + k0 + scol],
                  &Bs[it * 2048 + wave * 512]);
        }
        __syncthreads();

#pragma unroll
        for (int kk = 0; kk < 2; ++kk) {
            s16x8 af[4], bf[4];
#pragma unroll
            for (int i = 0; i < 4; ++i)
                af[i] = *(const s16x8*)&As[(wr * 64 + i * 16 + fr) * 64 + kk * 32 + fk];
#pragma unroll
            for (int j = 0; j < 4; ++j)
                bf[j] = *(const s16x8*)&Bs[(wc * 64 + j * 16 + fr) * 64 + kk * 32 + fk];
#pragma unroll
            for (int i = 0; i < 4; ++i)
#pragma unroll
                for (int j = 0; j < 4; ++j)
                    acc[i][j] = __builtin_amdgcn_mfma_f32_16x16x32_bf16(
                        af[i], bf[j], acc[i][j], 0, 0, 0);
        }
        __syncthreads();
    }

    const int r0 = bm + wr * 64 + (lane >> 4) * 4;
    const int c0 = bn + wc * 64 + (lane & 15);
    const float* resf          = (const float*)res;
    const unsigned short* resh = (const unsigned short*)res;
    float* outf          = (float*)out;
    unsigned short* outh = (unsigned short*)out;
#pragma unroll
    for (int i = 0; i < 4; ++i)
#pragma unroll
        for (int j = 0; j < 4; ++j) {
            const int col = c0 + j * 16;
            const float bcol = bias[col];
#pragma unroll
            for (int r = 0; r < 4; ++r) {
                const int row = r0 + i * 16 + r;
                float v = acc[i][j][r] + bcol;
                if (RES == 1) v += resf[(size_t)row * N + col];
                if (RES == 2) v += b2f(resh[(size_t)row * N + col]);
                if (RELU)     v = fmaxf(v, 0.f);
                if (OUTF) outf[(size_t)row * N + col] = v;
                else      outh[(size_t)row * N + col] = f2b(v);
            }
        }
}

// ---------------------------------------------------------------------------
__global__ __launch_bounds__(256)
void tpose(const float* __restrict__ in, unsigned short* __restrict__ out, int K, int N)
{
    __shared__ float T[64][65];
    const int tid = threadIdx.x;
    const int k0 = blockIdx.y * 64, n0 = blockIdx.x * 64;
    const int c = tid & 63, rb = tid >> 6;
#pragma unroll
    for (int it = 0; it < 16; ++it) {
        const int r = it * 4 + rb;
        T[r][c] = in[(size_t)(k0 + r) * N + n0 + c];
    }
    __syncthreads();
#pragma unroll
    for (int it = 0; it < 16; ++it) {
        const int r = it * 4 + rb;
        out[(size_t)(n0 + r) * K + k0 + c] = f2b(T[c][r]);
    }
}

__global__ __launch_bounds__(256)
void cvt_bf16(const float* __restrict__ in, unsigned short* __restrict__ out, int n4)
{
    const int i = blockIdx.x * 256 + threadIdx.x;
    if (i >= n4) return;
    const float4 v = ((const float4*)in)[i];
    ushort4 o;
    o.x = f2b(v.x); o.y = f2b(v.y); o.z = f2b(v.z); o.w = f2b(v.w);
    ((ushort4*)out)[i] = o;
}

__global__ __launch_bounds__(256)
void pack_bias(const float* __restrict__ bq, const float* __restrict__ bk,
               const float* __restrict__ bv, float* __restrict__ o)
{
    const int i = blockIdx.x * 256 + threadIdx.x;
    if (i < 1024) o[i] = bq[i];
    else if (i < 2048) o[i] = bk[i - 1024];
    else if (i < 3072) o[i] = bv[i - 2048];
}

// ---------------------------------------------------------------------------
// MFMA flash attention. qkv: [B*S][3072] bf16 rows = [q|k|v].
// Block = (64 q-rows, head, batch), 4 waves, wave owns 16-row q strip.
// Per 64-key tile: QK^T (8 mfma) -> wave-local online softmax -> PV (8 mfma).
// K/Q staged via global_load_lds with pre-swizzled source; V reg-staged
// transposed into Vt[dh][kv]; all LDS tiles use sidx() swizzle.
// ---------------------------------------------------------------------------
__global__ __launch_bounds__(256)
void attn_mfma(const unsigned short* __restrict__ qkv, const int* __restrict__ mask,
               unsigned short* __restrict__ o)
{
    const int b = blockIdx.z, h = blockIdx.y, q0 = blockIdx.x * 64;
    __shared__ unsigned short Qs[4096];
    __shared__ unsigned short Ks[4096];
    __shared__ unsigned short Vt[4096];
    __shared__ unsigned short Ps[4096];
    const int tid = threadIdx.x, wave = tid >> 6, lane = tid & 63;
    const int grp = lane >> 4, l16 = lane & 15;

    // ---- stage Q (once) ----
#pragma unroll
    for (int it = 0; it < 2; ++it) {
        const int slot = it * 256 + tid;
        const int row = slot >> 3, dhb = slot & 7;
        const int src = (dhb ^ ((row + (row >> 3)) & 7)) * 8;
        gld16(&qkv[(size_t)(b * SS + q0 + row) * 3072 + h * DHH + src],
              &Qs[(it * 256 + wave * 64) * 8]);
    }
    __syncthreads();
    const s16x8 aq0 = *(const s16x8*)&Qs[sidx(wave * 16 + l16, grp * 8)];
    const s16x8 aq1 = *(const s16x8*)&Qs[sidx(wave * 16 + l16, 32 + grp * 8)];

    f32x4 accO[4];
#pragma unroll
    for (int j = 0; j < 4; ++j) accO[j] = (f32x4){0.f, 0.f, 0.f, 0.f};
    float mrow[4] = {-1e30f, -1e30f, -1e30f, -1e30f};
    float lrow[4] = {0.f, 0.f, 0.f, 0.f};

    for (int kt = 0; kt < SS / 64; ++kt) {
        const int kv0 = kt * 64;
        __syncthreads();   // prev tile's reads done -> safe to restage
        // stage K (direct-to-LDS, source pre-swizzled)
#pragma unroll
        for (int it = 0; it < 2; ++it) {
            const int slot = it * 256 + tid;
            const int row = slot >> 3, dhb = slot & 7;
            const int src = (dhb ^ ((row + (row >> 3)) & 7)) * 8;
            gld16(&qkv[(size_t)(b * SS + kv0 + row) * 3072 + 1024 + h * DHH + src],
                  &Ks[(it * 256 + wave * 64) * 8]);
        }
        // stage V transposed (reg-staged; sigma swizzle rotates banks per element)
#pragma unroll
        for (int it = 0; it < 2; ++it) {
            const int vec = it * 256 + tid;
            const int kv = vec >> 3, dhb = vec & 7;
            const s16x8 vv = *(const s16x8*)
                &qkv[(size_t)(b * SS + kv0 + kv) * 3072 + 2048 + h * DHH + dhb * 8];
#pragma unroll
            for (int t = 0; t < 8; ++t)
                Vt[sidx(dhb * 8 + t, kv)] = (unsigned short)vv[t];
        }
        // key mask -> additive values (per lane: 4 cols)
        float madd[4];
#pragma unroll
        for (int j = 0; j < 4; ++j)
            madd[j] = mask[b * SS + kv0 + j * 16 + l16] ? 0.f : -1e9f;
        __syncthreads();   // staging visible (vmcnt drained by compiler)

        // ---- QK^T ----
        f32x4 sv[4];
#pragma unroll
        for (int j = 0; j < 4; ++j) {
            const s16x8 bk0 = *(const s16x8*)&Ks[sidx(j * 16 + l16, grp * 8)];
            const s16x8 bk1 = *(const s16x8*)&Ks[sidx(j * 16 + l16, 32 + grp * 8)];
            f32x4 z = (f32x4){0.f, 0.f, 0.f, 0.f};
            z = __builtin_amdgcn_mfma_f32_16x16x32_bf16(aq0, bk0, z, 0, 0, 0);
            z = __builtin_amdgcn_mfma_f32_16x16x32_bf16(aq1, bk1, z, 0, 0, 0);
            sv[j] = z;
        }
#pragma unroll
        for (int j = 0; j < 4; ++j)
#pragma unroll
            for (int r = 0; r < 4; ++r)
                sv[j][r] = sv[j][r] * 0.125f + madd[j];

        // ---- online softmax (rows spread over the 16 lanes of each grp) ----
#pragma unroll
        for (int r = 0; r < 4; ++r) {
            float mx = fmaxf(fmaxf(sv[0][r], sv[1][r]), fmaxf(sv[2][r], sv[3][r]));
#pragma unroll
            for (int off = 1; off < 16; off <<= 1)
                mx = fmaxf(mx, __shfl_xor(mx, off));
            const float mnew = fmaxf(mrow[r], mx);
            const float corr = __expf(mrow[r] - mnew);
            const int prow = wave * 16 + grp * 4 + r;
            float ps = 0.f;
#pragma unroll
            for (int j = 0; j < 4; ++j) {
                const float p = __expf(sv[j][r] - mnew);
                ps += p;
                Ps[sidx(prow, l16 + 16 * j)] = f2b(p);
            }
#pragma unroll
            for (int off = 1; off < 16; off <<= 1)
                ps += __shfl_xor(ps, off);
            lrow[r] = lrow[r] * corr + ps;
            mrow[r] = mnew;
#pragma unroll
            for (int j = 0; j < 4; ++j) accO[j][r] *= corr;
        }

        // ---- PV (P strip is wave-private; wave-synchronous, lgkmcnt-ordered) ----
        const s16x8 pa0 = *(const s16x8*)&Ps[sidx(wave * 16 + l16, grp * 8)];
        const s16x8 pa1 = *(const s16x8*)&Ps[sidx(wave * 16 + l16, 32 + grp * 8)];
#pragma unroll
        for (int j = 0; j < 4; ++j) {
            const s16x8 vb0 = *(const s16x8*)&Vt[sidx(j * 16 + l16, grp * 8)];
            const s16x8 vb1 = *(const s16x8*)&Vt[sidx(j * 16 + l16, 32 + grp * 8)];
            accO[j] = __builtin_amdgcn_mfma_f32_16x16x32_bf16(pa0, vb0, accO[j], 0, 0, 0);
            accO[j] = __builtin_amdgcn_mfma_f32_16x16x32_bf16(pa1, vb1, accO[j], 0, 0, 0);
        }
    }

    // ---- epilogue ----
#pragma unroll
    for (int r = 0; r < 4; ++r) {
        const float inv = 1.0f / lrow[r];
        const int row = q0 + wave * 16 + grp * 4 + r;
#pragma unroll
        for (int j = 0; j < 4; ++j)
            o[(size_t)(b * SS + row) * DD + h * DHH + j * 16 + l16] =
                f2b(accO[j][r] * inv);
    }
}

// ---------------------------------------------------------------------------
template <int OUTBF>
__global__ __launch_bounds__(256)
void ln_kernel(const float* __restrict__ x, const float* __restrict__ g,
               const float* __restrict__ beta, void* __restrict__ outv)
{
    const int row = blockIdx.x;
    const int tid = threadIdx.x;
    const float4 xl = reinterpret_cast<const float4*>(x + (size_t)row * DD)[tid];
    float s  = xl.x + xl.y + xl.z + xl.w;
    float sq = xl.x * xl.x + xl.y * xl.y + xl.z * xl.z + xl.w * xl.w;
#pragma unroll
    for (int off = 1; off < 64; off <<= 1) {
        s  += __shfl_xor(s, off);
        sq += __shfl_xor(sq, off);
    }
    __shared__ float ssum[4], ssq[4];
    const int wid = tid >> 6;
    if ((tid & 63) == 0) { ssum[wid] = s; ssq[wid] = sq; }
    __syncthreads();
    s  = ssum[0] + ssum[1] + ssum[2] + ssum[3];
    sq = ssq[0]  + ssq[1]  + ssq[2]  + ssq[3];
    const float mean = s * (1.0f / DD);
    const float var  = fmaxf(sq * (1.0f / DD) - mean * mean, 0.0f);
    const float rstd = rsqrtf(var + 1e-5f);
    const float4 gv = reinterpret_cast<const float4*>(g)[tid];
    const float4 bv = reinterpret_cast<const float4*>(beta)[tid];
    float4 ov;
    ov.x = (xl.x - mean) * rstd * gv.x + bv.x;
    ov.y = (xl.y - mean) * rstd * gv.y + bv.y;
    ov.z = (xl.z - mean) * rstd * gv.z + bv.z;
    ov.w = (xl.w - mean) * rstd * gv.w + bv.w;
    if (OUTBF) {
        ushort4 o4;
        o4.x = f2b(ov.x); o4.y = f2b(ov.y); o4.z = f2b(ov.z); o4.w = f2b(ov.w);
        reinterpret_cast<ushort4*>(outv)[(size_t)row * 256 + tid] = o4;
    } else {
        reinterpret_cast<float4*>(outv)[(size_t)row * 256 + tid] = ov;
    }
}

// ---------------------------------------------------------------------------
extern "C" void kernel_launch(void* const* d_in, const int* in_sizes, int n_in,
                              void* d_out, int out_size, void* d_ws, size_t ws_size,
                              hipStream_t stream)
{
    (void)in_sizes; (void)n_in; (void)out_size; (void)ws_size;

    const float* x     = (const float*)d_in[0];
    const int*   mask  = (const int*)  d_in[1];
    const float* wq    = (const float*)d_in[2];
    const float* bq    = (const float*)d_in[3];
    const float* wk    = (const float*)d_in[4];
    const float* bk    = (const float*)d_in[5];
    const float* wv    = (const float*)d_in[6];
    const float* bv    = (const float*)d_in[7];
    const float* wo    = (const float*)d_in[8];
    const float* bo    = (const float*)d_in[9];
    const float* ln1_g = (const float*)d_in[10];
    const float* ln1_b = (const float*)d_in[11];
    const float* w1    = (const float*)d_in[12];
    const float* b1    = (const float*)d_in[13];
    const float* w2    = (const float*)d_in[14];
    const float* b2    = (const float*)d_in[15];
    const float* ln2_g = (const float*)d_in[16];
    const float* ln2_b = (const float*)d_in[17];

    float* out = (float*)d_out;
    char*  wsb = (char*)d_ws;
    const size_t MB = 1u << 20;

    unsigned short* wqkvT = (unsigned short*)(wsb + 0);        // [3072][1024]
    unsigned short* woT   = (unsigned short*)(wsb + 6 * MB);   // [1024][1024]
    unsigned short* w1T   = (unsigned short*)(wsb + 8 * MB);   // [2048][1024]
    unsigned short* w2T   = (unsigned short*)(wsb + 12 * MB);  // [1024][2048]
    float*          bqkv  = (float*)(wsb + 16 * MB);           // [3072]
    unsigned short* qkvb  = (unsigned short*)(wsb + 17 * MB);  // [4096][3072] bf16
    unsigned short* xb    = (unsigned short*)(wsb + 41 * MB);  // [4096][1024] bf16
    unsigned short* ab16  = xb;
    float*          t0    = (float*)(wsb + 17 * MB);
    unsigned short* hb16  = (unsigned short*)(wsb + 33 * MB);
    unsigned short* f1b   = (unsigned short*)(wsb + 41 * MB);
    float*          t1    = (float*)(wsb + 17 * MB);

    cvt_bf16<<<4096, 256, 0, stream>>>(x, xb, MM * DD / 4);
    tpose<<<dim3(16, 16), 256, 0, stream>>>(wq, wqkvT, DD, DD);
    tpose<<<dim3(16, 16), 256, 0, stream>>>(wk, wqkvT + 1024 * 1024, DD, DD);
    tpose<<<dim3(16, 16), 256, 0, stream>>>(wv, wqkvT + 2 * 1024 * 1024, DD, DD);
    tpose<<<dim3(16, 16), 256, 0, stream>>>(wo, woT, DD, DD);
    tpose<<<dim3(32, 16), 256, 0, stream>>>(w1, w1T, DD, 2 * DD);
    tpose<<<dim3(16, 32), 256, 0, stream>>>(w2, w2T, 2 * DD, DD);
    pack_bias<<<12, 256, 0, stream>>>(bq, bk, bv, bqkv);

    mgemm<0, 0, 0><<<dim3(24, 32), 256, 0, stream>>>(xb, wqkvT, bqkv, nullptr, qkvb,
                                                     MM, 3 * DD, DD);
    attn_mfma<<<dim3(SS / 64, HH, BB), 256, 0, stream>>>(qkvb, mask, ab16);
    mgemm<0, 1, 1><<<dim3(8, 32), 256, 0, stream>>>(ab16, woT, bo, x, t0, MM, DD, DD);
    ln_kernel<1><<<MM, 256, 0, stream>>>(t0, ln1_g, ln1_b, hb16);
    mgemm<1, 0, 0><<<dim3(16, 32), 256, 0, stream>>>(hb16, w1T, b1, nullptr, f1b,
                                                     MM, 2 * DD, DD);
    mgemm<0, 2, 1><<<dim3(8, 32), 256, 0, stream>>>(f1b, w2T, b2, hb16, t1,
                                                    MM, DD, 2 * DD);
    ln_kernel<0><<<MM, 256, 0, stream>>>(t1, ln2_g, ln2_b, out);
}

// Round 5
// 298.690 us; speedup vs baseline: 6.2655x; 1.1106x over previous
//
#include <hip/hip_runtime.h>
#include <math.h>

#define BB  2
#define SS  2048
#define DD  1024
#define HH  16
#define DHH 64
#define MM  (BB * SS)   // 4096 rows

typedef float f32x4 __attribute__((ext_vector_type(4)));
typedef short s16x8 __attribute__((ext_vector_type(8)));

__device__ __forceinline__ unsigned short f2b(float f) {
    union { float f; unsigned u; } v; v.f = f;
    unsigned r = v.u + 0x7fffu + ((v.u >> 16) & 1u);
    return (unsigned short)(r >> 16);
}
__device__ __forceinline__ float b2f(unsigned short u) {
    union { unsigned u; float f; } v; v.u = ((unsigned)u) << 16;
    return v.f;
}

typedef __attribute__((address_space(1))) void gv_t;
typedef __attribute__((address_space(3))) void lv_t;
__device__ __forceinline__ void gld16(const void* g, void* l) {
    __builtin_amdgcn_global_load_lds((gv_t*)(void*)g, (lv_t*)l, 16, 0, 0);
}

// LDS swizzle for 64-col bf16 tiles: XOR sigma(row)=(row+row>>3)&7 on 16B-block bits.
__device__ __forceinline__ int sidx(int row, int col) {
    return row * 64 + (col ^ (((row + (row >> 3)) & 7) << 3));
}

// ---------------------------------------------------------------------------
// bf16 MFMA GEMM (m97 structure): C[M,N] = A[M,K] @ B^T[N,K] + bias (+res)(relu)
// VS=1: QKV mode — cols<2048 -> out (stride outN), cols>=2048 -> vt transposed
// per head: vt[b][h][dh][s], i.e. [(b*16+h)*64+dh][2048].
// ---------------------------------------------------------------------------
template <int RELU, int RES, int OUTF, int VS>
__global__ __launch_bounds__(256)
void mgemm(const unsigned short* __restrict__ A, const unsigned short* __restrict__ B,
           const float* __restrict__ bias, const void* __restrict__ res,
           void* __restrict__ out, unsigned short* __restrict__ vt,
           int M, int N, int K, int outN)
{
    __shared__ short As[128 * 64];
    __shared__ short Bs[128 * 64];

    const int tid  = threadIdx.x;
    const int wave = tid >> 6, lane = tid & 63;
    const int bm = blockIdx.y * 128, bn = blockIdx.x * 128;
    const int srow = tid >> 3;
    const int scol = (tid & 7) * 8;
    const int wr = wave >> 1, wc = wave & 1;
    const int fr = lane & 15;
    const int fk = (lane >> 4) * 8;

    f32x4 acc[4][4];
#pragma unroll
    for (int i = 0; i < 4; ++i)
#pragma unroll
        for (int j = 0; j < 4; ++j) acc[i][j] = (f32x4){0.f, 0.f, 0.f, 0.f};

    for (int k0 = 0; k0 < K; k0 += 64) {
#pragma unroll
        for (int it = 0; it < 4; ++it) {
            gld16(&A[(size_t)(bm + it * 32 + srow) * K + k0 + scol],
                  &As[it * 2048 + wave * 512]);
            gld16(&B[(size_t)(bn + it * 32 + srow) * K + k0 + scol],
                  &Bs[it * 2048 + wave * 512]);
        }
        __syncthreads();

#pragma unroll
        for (int kk = 0; kk < 2; ++kk) {
            s16x8 af[4], bf[4];
#pragma unroll
            for (int i = 0; i < 4; ++i)
                af[i] = *(const s16x8*)&As[(wr * 64 + i * 16 + fr) * 64 + kk * 32 + fk];
#pragma unroll
            for (int j = 0; j < 4; ++j)
                bf[j] = *(const s16x8*)&Bs[(wc * 64 + j * 16 + fr) * 64 + kk * 32 + fk];
#pragma unroll
            for (int i = 0; i < 4; ++i)
#pragma unroll
                for (int j = 0; j < 4; ++j)
                    acc[i][j] = __builtin_amdgcn_mfma_f32_16x16x32_bf16(
                        af[i], bf[j], acc[i][j], 0, 0, 0);
        }
        __syncthreads();
    }

    const int r0 = bm + wr * 64 + (lane >> 4) * 4;
    const int c0 = bn + wc * 64 + (lane & 15);
    const float* resf          = (const float*)res;
    const unsigned short* resh = (const unsigned short*)res;
    float* outf          = (float*)out;
    unsigned short* outh = (unsigned short*)out;

    if (VS == 1 && bn >= 2048) {
        // V columns -> per-head transposed store
#pragma unroll
        for (int i = 0; i < 4; ++i)
#pragma unroll
            for (int j = 0; j < 4; ++j) {
                const int col = c0 + j * 16;
                const int hh = (col >> 6) & 15, dh = col & 63;
                const float bcol = bias[col];
#pragma unroll
                for (int r = 0; r < 4; ++r) {
                    const int row = r0 + i * 16 + r;
                    const int bb = row >> 11, s = row & 2047;
                    vt[(size_t)(((bb * 16 + hh) * 64) + dh) * 2048 + s] =
                        f2b(acc[i][j][r] + bcol);
                }
            }
        return;
    }

#pragma unroll
    for (int i = 0; i < 4; ++i)
#pragma unroll
        for (int j = 0; j < 4; ++j) {
            const int col = c0 + j * 16;
            const float bcol = bias[col];
#pragma unroll
            for (int r = 0; r < 4; ++r) {
                const int row = r0 + i * 16 + r;
                float v = acc[i][j][r] + bcol;
                if (RES == 1) v += resf[(size_t)row * outN + col];
                if (RES == 2) v += b2f(resh[(size_t)row * outN + col]);
                if (RELU)     v = fmaxf(v, 0.f);
                if (OUTF) outf[(size_t)row * outN + col] = v;
                else      outh[(size_t)row * outN + col] = f2b(v);
            }
        }
}

// ---------------------------------------------------------------------------
__global__ __launch_bounds__(256)
void tpose(const float* __restrict__ in, unsigned short* __restrict__ out, int K, int N)
{
    __shared__ float T[64][65];
    const int tid = threadIdx.x;
    const int k0 = blockIdx.y * 64, n0 = blockIdx.x * 64;
    const int c = tid & 63, rb = tid >> 6;
#pragma unroll
    for (int it = 0; it < 16; ++it) {
        const int r = it * 4 + rb;
        T[r][c] = in[(size_t)(k0 + r) * N + n0 + c];
    }
    __syncthreads();
#pragma unroll
    for (int it = 0; it < 16; ++it) {
        const int r = it * 4 + rb;
        out[(size_t)(n0 + r) * K + k0 + c] = f2b(T[c][r]);
    }
}

__global__ __launch_bounds__(256)
void cvt_bf16(const float* __restrict__ in, unsigned short* __restrict__ out, int n4)
{
    const int i = blockIdx.x * 256 + threadIdx.x;
    if (i >= n4) return;
    const float4 v = ((const float4*)in)[i];
    ushort4 o;
    o.x = f2b(v.x); o.y = f2b(v.y); o.z = f2b(v.z); o.w = f2b(v.w);
    ((ushort4*)out)[i] = o;
}

__global__ __launch_bounds__(256)
void pack_bias(const float* __restrict__ bq, const float* __restrict__ bk,
               const float* __restrict__ bv, float* __restrict__ o)
{
    const int i = blockIdx.x * 256 + threadIdx.x;
    if (i < 1024) o[i] = bq[i];
    else if (i < 2048) o[i] = bk[i - 1024];
    else if (i < 3072) o[i] = bv[i - 2048];
}

// ---------------------------------------------------------------------------
// MFMA flash attention v3. qk: [B*S][2048] bf16 = [q|k]; vt: [B][H][64][2048].
// Block = (128 q-rows, head, batch), 8 waves; wave owns a 16-row q strip.
// All LDS tiles sigma-swizzled; staging via global_load_lds w/ pre-swizzled src.
// Fragment paths identical to the round-3-verified kernel.
// ---------------------------------------------------------------------------
__global__ __launch_bounds__(512)
void attn_mfma(const unsigned short* __restrict__ qk,
               const unsigned short* __restrict__ vt,
               const int* __restrict__ mask, unsigned short* __restrict__ o)
{
    const int b = blockIdx.z, h = blockIdx.y, q0 = blockIdx.x * 128;
    __shared__ unsigned short Qs[8192];   // 128x64
    __shared__ unsigned short Ks[4096];   // 64x64
    __shared__ unsigned short Vs[4096];   // 64x64 (rows=dh, cols=kv)
    __shared__ unsigned short Ps[8192];   // per-wave 16x64 strips
    __shared__ float maskf[64];
    const int tid = threadIdx.x, wave = tid >> 6, lane = tid & 63;
    const int grp = lane >> 4, l16 = lane & 15;

    const size_t qkbase = (size_t)(b * SS) * 2048 + h * DHH;

    // ---- stage Q (once): rows q0..q0+127 ----
#pragma unroll
    for (int it = 0; it < 2; ++it) {
        const int slot = it * 512 + tid;
        const int row = slot >> 3, dhb = slot & 7;
        const int src = (dhb ^ ((row + (row >> 3)) & 7)) * 8;
        gld16(&qk[qkbase + (size_t)(q0 + row) * 2048 + src],
              &Qs[it * 4096 + wave * 512]);
    }
    // fixed per-thread staging coords
    const int krow = tid >> 3, kdhb = tid & 7;
    const int ksrc = (kdhb ^ ((krow + (krow >> 3)) & 7)) * 8;

    __syncthreads();
    const s16x8 aq0 = *(const s16x8*)&Qs[sidx(wave * 16 + l16, grp * 8)];
    const s16x8 aq1 = *(const s16x8*)&Qs[sidx(wave * 16 + l16, 32 + grp * 8)];

    f32x4 accO[4];
#pragma unroll
    for (int j = 0; j < 4; ++j) accO[j] = (f32x4){0.f, 0.f, 0.f, 0.f};
    float mrow[4] = {-1e30f, -1e30f, -1e30f, -1e30f};
    float lrow[4] = {0.f, 0.f, 0.f, 0.f};
    const float SC = 0.18033688f;          // 0.125 * log2(e)
    const float MNEG = -1.442695e9f;       // -1e9 * log2(e)

    for (int kt = 0; kt < SS / 64; ++kt) {
        const int kv0 = kt * 64;
        __syncthreads();   // prev tile reads done
        gld16(&qk[qkbase + (size_t)(kv0 + krow) * 2048 + 1024 + ksrc], &Ks[wave * 512]);
        gld16(&vt[(size_t)((b * HH + h) * 64 + krow) * 2048 + kv0 + ksrc], &Vs[wave * 512]);
        if (tid < 64) maskf[tid] = mask[b * SS + kv0 + tid] ? 0.f : MNEG;
        __syncthreads();   // staging + maskf visible

        float madd[4];
#pragma unroll
        for (int j = 0; j < 4; ++j) madd[j] = maskf[j * 16 + l16];

        // ---- QK^T ----
        f32x4 sv[4];
        __builtin_amdgcn_s_setprio(1);
#pragma unroll
        for (int j = 0; j < 4; ++j) {
            const s16x8 bk0 = *(const s16x8*)&Ks[sidx(j * 16 + l16, grp * 8)];
            const s16x8 bk1 = *(const s16x8*)&Ks[sidx(j * 16 + l16, 32 + grp * 8)];
            f32x4 z = (f32x4){0.f, 0.f, 0.f, 0.f};
            z = __builtin_amdgcn_mfma_f32_16x16x32_bf16(aq0, bk0, z, 0, 0, 0);
            z = __builtin_amdgcn_mfma_f32_16x16x32_bf16(aq1, bk1, z, 0, 0, 0);
            sv[j] = z;
        }
        __builtin_amdgcn_s_setprio(0);
#pragma unroll
        for (int j = 0; j < 4; ++j)
#pragma unroll
            for (int r = 0; r < 4; ++r)
                sv[j][r] = sv[j][r] * SC + madd[j];

        // ---- online softmax (exp2 domain) ----
#pragma unroll
        for (int r = 0; r < 4; ++r) {
            float mx = fmaxf(fmaxf(sv[0][r], sv[1][r]), fmaxf(sv[2][r], sv[3][r]));
#pragma unroll
            for (int off = 1; off < 16; off <<= 1)
                mx = fmaxf(mx, __shfl_xor(mx, off));
            const float mnew = fmaxf(mrow[r], mx);
            const float corr = __builtin_amdgcn_exp2f(mrow[r] - mnew);
            const int prow = grp * 4 + r;   // wave-local row
            float ps = 0.f;
#pragma unroll
            for (int j = 0; j < 4; ++j) {
                const float p = __builtin_amdgcn_exp2f(sv[j][r] - mnew);
                ps += p;
                Ps[wave * 1024 + sidx(prow, l16 + 16 * j)] = f2b(p);
            }
#pragma unroll
            for (int off = 1; off < 16; off <<= 1)
                ps += __shfl_xor(ps, off);
            lrow[r] = lrow[r] * corr + ps;
            mrow[r] = mnew;
#pragma unroll
            for (int j = 0; j < 4; ++j) accO[j][r] *= corr;
        }

        // ---- PV (wave-private P strip; wave-synchronous, lgkmcnt-ordered) ----
        const s16x8 pa0 = *(const s16x8*)&Ps[wave * 1024 + sidx(l16, grp * 8)];
        const s16x8 pa1 = *(const s16x8*)&Ps[wave * 1024 + sidx(l16, 32 + grp * 8)];
        __builtin_amdgcn_s_setprio(1);
#pragma unroll
        for (int j = 0; j < 4; ++j) {
            const s16x8 vb0 = *(const s16x8*)&Vs[sidx(j * 16 + l16, grp * 8)];
            const s16x8 vb1 = *(const s16x8*)&Vs[sidx(j * 16 + l16, 32 + grp * 8)];
            accO[j] = __builtin_amdgcn_mfma_f32_16x16x32_bf16(pa0, vb0, accO[j], 0, 0, 0);
            accO[j] = __builtin_amdgcn_mfma_f32_16x16x32_bf16(pa1, vb1, accO[j], 0, 0, 0);
        }
        __builtin_amdgcn_s_setprio(0);
    }

    // ---- epilogue ----
#pragma unroll
    for (int r = 0; r < 4; ++r) {
        const float inv = 1.0f / lrow[r];
        const int row = q0 + wave * 16 + grp * 4 + r;
#pragma unroll
        for (int j = 0; j < 4; ++j)
            o[(size_t)(b * SS + row) * DD + h * DHH + j * 16 + l16] =
                f2b(accO[j][r] * inv);
    }
}

// ---------------------------------------------------------------------------
template <int OUTBF>
__global__ __launch_bounds__(256)
void ln_kernel(const float* __restrict__ x, const float* __restrict__ g,
               const float* __restrict__ beta, void* __restrict__ outv)
{
    const int row = blockIdx.x;
    const int tid = threadIdx.x;
    const float4 xl = reinterpret_cast<const float4*>(x + (size_t)row * DD)[tid];
    float s  = xl.x + xl.y + xl.z + xl.w;
    float sq = xl.x * xl.x + xl.y * xl.y + xl.z * xl.z + xl.w * xl.w;
#pragma unroll
    for (int off = 1; off < 64; off <<= 1) {
        s  += __shfl_xor(s, off);
        sq += __shfl_xor(sq, off);
    }
    __shared__ float ssum[4], ssq[4];
    const int wid = tid >> 6;
    if ((tid & 63) == 0) { ssum[wid] = s; ssq[wid] = sq; }
    __syncthreads();
    s  = ssum[0] + ssum[1] + ssum[2] + ssum[3];
    sq = ssq[0]  + ssq[1]  + ssq[2]  + ssq[3];
    const float mean = s * (1.0f / DD);
    const float var  = fmaxf(sq * (1.0f / DD) - mean * mean, 0.0f);
    const float rstd = rsqrtf(var + 1e-5f);
    const float4 gv = reinterpret_cast<const float4*>(g)[tid];
    const float4 bv = reinterpret_cast<const float4*>(beta)[tid];
    float4 ov;
    ov.x = (xl.x - mean) * rstd * gv.x + bv.x;
    ov.y = (xl.y - mean) * rstd * gv.y + bv.y;
    ov.z = (xl.z - mean) * rstd * gv.z + bv.z;
    ov.w = (xl.w - mean) * rstd * gv.w + bv.w;
    if (OUTBF) {
        ushort4 o4;
        o4.x = f2b(ov.x); o4.y = f2b(ov.y); o4.z = f2b(ov.z); o4.w = f2b(ov.w);
        reinterpret_cast<ushort4*>(outv)[(size_t)row * 256 + tid] = o4;
    } else {
        reinterpret_cast<float4*>(outv)[(size_t)row * 256 + tid] = ov;
    }
}

// ---------------------------------------------------------------------------
extern "C" void kernel_launch(void* const* d_in, const int* in_sizes, int n_in,
                              void* d_out, int out_size, void* d_ws, size_t ws_size,
                              hipStream_t stream)
{
    (void)in_sizes; (void)n_in; (void)out_size; (void)ws_size;

    const float* x     = (const float*)d_in[0];
    const int*   mask  = (const int*)  d_in[1];
    const float* wq    = (const float*)d_in[2];
    const float* bq    = (const float*)d_in[3];
    const float* wk    = (const float*)d_in[4];
    const float* bk    = (const float*)d_in[5];
    const float* wv    = (const float*)d_in[6];
    const float* bv    = (const float*)d_in[7];
    const float* wo    = (const float*)d_in[8];
    const float* bo    = (const float*)d_in[9];
    const float* ln1_g = (const float*)d_in[10];
    const float* ln1_b = (const float*)d_in[11];
    const float* w1    = (const float*)d_in[12];
    const float* b1    = (const float*)d_in[13];
    const float* w2    = (const float*)d_in[14];
    const float* b2    = (const float*)d_in[15];
    const float* ln2_g = (const float*)d_in[16];
    const float* ln2_b = (const float*)d_in[17];

    float* out = (float*)d_out;
    char*  wsb = (char*)d_ws;
    const size_t MB = 1u << 20;

    // weights (live whole launch): 0..16 MB; bias at 16
    unsigned short* wqkvT = (unsigned short*)(wsb + 0);        // [3072][1024]
    unsigned short* woT   = (unsigned short*)(wsb + 6 * MB);   // [1024][1024]
    unsigned short* w1T   = (unsigned short*)(wsb + 8 * MB);   // [2048][1024]
    unsigned short* w2T   = (unsigned short*)(wsb + 12 * MB);  // [1024][2048]
    float*          bqkv  = (float*)(wsb + 16 * MB);           // [3072]
    // activations
    unsigned short* qkb   = (unsigned short*)(wsb + 17 * MB);  // [4096][2048] (17..33)
    unsigned short* vtb   = (unsigned short*)(wsb + 33 * MB);  // [2*16*64][2048] (33..41)
    unsigned short* xb    = (unsigned short*)(wsb + 41 * MB);  // [4096][1024] (41..49)
    unsigned short* ab16  = xb;                                // attn out reuses xb
    float*          t0    = (float*)(wsb + 17 * MB);           // (17..33) qkb dead
    unsigned short* hb16  = (unsigned short*)(wsb + 33 * MB);  // (33..41) vtb dead
    unsigned short* f1b   = (unsigned short*)(wsb + 41 * MB);  // [4096][2048] (41..57)
    float*          t1    = (float*)(wsb + 17 * MB);           // (17..33) t0 dead

    cvt_bf16<<<4096, 256, 0, stream>>>(x, xb, MM * DD / 4);
    tpose<<<dim3(16, 16), 256, 0, stream>>>(wq, wqkvT, DD, DD);
    tpose<<<dim3(16, 16), 256, 0, stream>>>(wk, wqkvT + 1024 * 1024, DD, DD);
    tpose<<<dim3(16, 16), 256, 0, stream>>>(wv, wqkvT + 2 * 1024 * 1024, DD, DD);
    tpose<<<dim3(16, 16), 256, 0, stream>>>(wo, woT, DD, DD);
    tpose<<<dim3(32, 16), 256, 0, stream>>>(w1, w1T, DD, 2 * DD);
    tpose<<<dim3(16, 32), 256, 0, stream>>>(w2, w2T, 2 * DD, DD);
    pack_bias<<<12, 256, 0, stream>>>(bq, bk, bv, bqkv);

    // fused QKV projection: q|k -> qkb [4096][2048], v -> vtb transposed per head
    mgemm<0, 0, 0, 1><<<dim3(24, 32), 256, 0, stream>>>(
        xb, wqkvT, bqkv, nullptr, qkb, vtb, MM, 3 * DD, DD, 2048);
    // flash attention
    attn_mfma<<<dim3(SS / 128, HH, BB), 512, 0, stream>>>(qkb, vtb, mask, ab16);
    // output projection + residual x
    mgemm<0, 1, 1, 0><<<dim3(8, 32), 256, 0, stream>>>(
        ab16, woT, bo, x, t0, nullptr, MM, DD, DD, DD);
    // LN1 -> bf16
    ln_kernel<1><<<MM, 256, 0, stream>>>(t0, ln1_g, ln1_b, hb16);
    // FFN
    mgemm<1, 0, 0, 0><<<dim3(16, 32), 256, 0, stream>>>(
        hb16, w1T, b1, nullptr, f1b, nullptr, MM, 2 * DD, DD, 2 * DD);
    mgemm<0, 2, 1, 0><<<dim3(8, 32), 256, 0, stream>>>(
        f1b, w2T, b2, hb16, t1, nullptr, MM, DD, 2 * DD, DD);
    // LN2 -> out
    ln_kernel<0><<<MM, 256, 0, stream>>>(t1, ln2_g, ln2_b, out);
}

// Round 6
// 298.473 us; speedup vs baseline: 6.2701x; 1.0007x over previous
//
#include <hip/hip_runtime.h>
#include <math.h>

#define BB  2
#define SS  2048
#define DD  1024
#define HH  16
#define DHH 64
#define MM  (BB * SS)   // 4096 rows

typedef float f32x4 __attribute__((ext_vector_type(4)));
typedef short s16x8 __attribute__((ext_vector_type(8)));

__device__ __forceinline__ unsigned short f2b(float f) {
    union { float f; unsigned u; } v; v.f = f;
    unsigned r = v.u + 0x7fffu + ((v.u >> 16) & 1u);
    return (unsigned short)(r >> 16);
}
__device__ __forceinline__ float b2f(unsigned short u) {
    union { unsigned u; float f; } v; v.u = ((unsigned)u) << 16;
    return v.f;
}

typedef __attribute__((address_space(1))) void gv_t;
typedef __attribute__((address_space(3))) void lv_t;
__device__ __forceinline__ void gld16(const void* g, void* l) {
    __builtin_amdgcn_global_load_lds((gv_t*)(void*)g, (lv_t*)l, 16, 0, 0);
}

// LDS swizzle for 64-col bf16 tiles: XOR sigma(row)=(row+row>>3)&7 on 16B-block bits.
__device__ __forceinline__ int sidx(int row, int col) {
    return row * 64 + (col ^ (((row + (row >> 3)) & 7) << 3));
}

// ---------------------------------------------------------------------------
// bf16 MFMA GEMM (m97 structure): C[M,N] = A[M,K] @ B^T[N,K] + bias (+res)(relu)
// VS=1: QKV mode — cols<2048 -> out (stride outN), cols>=2048 -> vt transposed
// per head: vt[b][h][dh][s].
// ---------------------------------------------------------------------------
template <int RELU, int RES, int OUTF, int VS>
__global__ __launch_bounds__(256)
void mgemm(const unsigned short* __restrict__ A, const unsigned short* __restrict__ B,
           const float* __restrict__ bias, const void* __restrict__ res,
           void* __restrict__ out, unsigned short* __restrict__ vt,
           int M, int N, int K, int outN)
{
    __shared__ short As[128 * 64];
    __shared__ short Bs[128 * 64];

    const int tid  = threadIdx.x;
    const int wave = tid >> 6, lane = tid & 63;
    const int bm = blockIdx.y * 128, bn = blockIdx.x * 128;
    const int srow = tid >> 3;
    const int scol = (tid & 7) * 8;
    const int wr = wave >> 1, wc = wave & 1;
    const int fr = lane & 15;
    const int fk = (lane >> 4) * 8;

    f32x4 acc[4][4];
#pragma unroll
    for (int i = 0; i < 4; ++i)
#pragma unroll
        for (int j = 0; j < 4; ++j) acc[i][j] = (f32x4){0.f, 0.f, 0.f, 0.f};

    for (int k0 = 0; k0 < K; k0 += 64) {
#pragma unroll
        for (int it = 0; it < 4; ++it) {
            gld16(&A[(size_t)(bm + it * 32 + srow) * K + k0 + scol],
                  &As[it * 2048 + wave * 512]);
            gld16(&B[(size_t)(bn + it * 32 + srow) * K + k0 + scol],
                  &Bs[it * 2048 + wave * 512]);
        }
        __syncthreads();

#pragma unroll
        for (int kk = 0; kk < 2; ++kk) {
            s16x8 af[4], bf[4];
#pragma unroll
            for (int i = 0; i < 4; ++i)
                af[i] = *(const s16x8*)&As[(wr * 64 + i * 16 + fr) * 64 + kk * 32 + fk];
#pragma unroll
            for (int j = 0; j < 4; ++j)
                bf[j] = *(const s16x8*)&Bs[(wc * 64 + j * 16 + fr) * 64 + kk * 32 + fk];
#pragma unroll
            for (int i = 0; i < 4; ++i)
#pragma unroll
                for (int j = 0; j < 4; ++j)
                    acc[i][j] = __builtin_amdgcn_mfma_f32_16x16x32_bf16(
                        af[i], bf[j], acc[i][j], 0, 0, 0);
        }
        __syncthreads();
    }

    const int r0 = bm + wr * 64 + (lane >> 4) * 4;
    const int c0 = bn + wc * 64 + (lane & 15);
    const float* resf          = (const float*)res;
    const unsigned short* resh = (const unsigned short*)res;
    float* outf          = (float*)out;
    unsigned short* outh = (unsigned short*)out;

    if (VS == 1 && bn >= 2048) {
#pragma unroll
        for (int i = 0; i < 4; ++i)
#pragma unroll
            for (int j = 0; j < 4; ++j) {
                const int col = c0 + j * 16;
                const int hh = (col >> 6) & 15, dh = col & 63;
                const float bcol = bias[col];
#pragma unroll
                for (int r = 0; r < 4; ++r) {
                    const int row = r0 + i * 16 + r;
                    const int bb = row >> 11, s = row & 2047;
                    vt[(size_t)(((bb * 16 + hh) * 64) + dh) * 2048 + s] =
                        f2b(acc[i][j][r] + bcol);
                }
            }
        return;
    }

#pragma unroll
    for (int i = 0; i < 4; ++i)
#pragma unroll
        for (int j = 0; j < 4; ++j) {
            const int col = c0 + j * 16;
            const float bcol = bias[col];
#pragma unroll
            for (int r = 0; r < 4; ++r) {
                const int row = r0 + i * 16 + r;
                float v = acc[i][j][r] + bcol;
                if (RES == 1) v += resf[(size_t)row * outN + col];
                if (RES == 2) v += b2f(resh[(size_t)row * outN + col]);
                if (RELU)     v = fmaxf(v, 0.f);
                if (OUTF) outf[(size_t)row * outN + col] = v;
                else      outh[(size_t)row * outN + col] = f2b(v);
            }
        }
}

// ---------------------------------------------------------------------------
// Fused prep: x->bf16, 6 weight transposes (fp32[K][N] -> bf16[N][K]), bias pack.
// ---------------------------------------------------------------------------
__global__ __launch_bounds__(256)
void prep(const float* __restrict__ x,
          const float* __restrict__ wq, const float* __restrict__ wk,
          const float* __restrict__ wv, const float* __restrict__ wo,
          const float* __restrict__ w1, const float* __restrict__ w2,
          const float* __restrict__ bq, const float* __restrict__ bk,
          const float* __restrict__ bv,
          unsigned short* __restrict__ xb, unsigned short* __restrict__ wqkvT,
          unsigned short* __restrict__ woT, unsigned short* __restrict__ w1T,
          unsigned short* __restrict__ w2T, float* __restrict__ bqkv)
{
    __shared__ float T[64][65];
    const int tid = threadIdx.x;
    int bid = blockIdx.x;

    if (bid < 4096) {   // x -> bf16
        const int i = bid * 256 + tid;
        const float4 v = ((const float4*)x)[i];
        ushort4 o4;
        o4.x = f2b(v.x); o4.y = f2b(v.y); o4.z = f2b(v.z); o4.w = f2b(v.w);
        ((ushort4*)xb)[i] = o4;
        return;
    }
    bid -= 4096;

    if (bid >= 2048) {  // bias pack, 12 blocks
        const int i = (bid - 2048) * 256 + tid;
        if (i < 1024) bqkv[i] = bq[i];
        else if (i < 2048) bqkv[i] = bk[i - 1024];
        else if (i < 3072) bqkv[i] = bv[i - 2048];
        return;
    }

    const float* src; unsigned short* dst; int K, N, nbx, sub;
    if (bid < 256)       { src = wq; dst = wqkvT;               K = 1024; N = 1024; nbx = 16; sub = bid; }
    else if (bid < 512)  { src = wk; dst = wqkvT + 1024 * 1024; K = 1024; N = 1024; nbx = 16; sub = bid - 256; }
    else if (bid < 768)  { src = wv; dst = wqkvT + 2048 * 1024; K = 1024; N = 1024; nbx = 16; sub = bid - 512; }
    else if (bid < 1024) { src = wo; dst = woT;                 K = 1024; N = 1024; nbx = 16; sub = bid - 768; }
    else if (bid < 1536) { src = w1; dst = w1T;                 K = 1024; N = 2048; nbx = 32; sub = bid - 1024; }
    else                 { src = w2; dst = w2T;                 K = 2048; N = 1024; nbx = 16; sub = bid - 1536; }

    const int n0 = (sub % nbx) * 64, k0 = (sub / nbx) * 64;
    const int c = tid & 63, rb = tid >> 6;
#pragma unroll
    for (int it = 0; it < 16; ++it) {
        const int r = it * 4 + rb;
        T[r][c] = src[(size_t)(k0 + r) * N + n0 + c];
    }
    __syncthreads();
#pragma unroll
    for (int it = 0; it < 16; ++it) {
        const int r = it * 4 + rb;
        dst[(size_t)(n0 + r) * K + k0 + c] = f2b(T[c][r]);
    }
}

// ---------------------------------------------------------------------------
// MFMA flash attention v4. qk: [B*S][2048] bf16 = [q|k]; vt: [B][H][64][2048].
// Block = (128 q-rows, head, batch), 8 waves; wave owns a 16-row q strip.
// Double-buffered K/V/mask staging (1 barrier/tile); MFMA ones-trick row sums;
// defer-max (THR=8, exp2 domain). Fragment paths = round-3/5-verified.
// ---------------------------------------------------------------------------
__global__ __launch_bounds__(512)
void attn_mfma(const unsigned short* __restrict__ qk,
               const unsigned short* __restrict__ vt,
               const int* __restrict__ mask, unsigned short* __restrict__ o)
{
    const int b = blockIdx.z, h = blockIdx.y, q0 = blockIdx.x * 128;
    __shared__ unsigned short Qs[8192];      // 128x64
    __shared__ unsigned short Ks[2][4096];   // dbuf 64x64
    __shared__ unsigned short Vs[2][4096];   // dbuf 64x64 (rows=dh, cols=kv)
    __shared__ unsigned short Ps[8192];      // per-wave 16x64 strips
    __shared__ float maskf[2][64];
    const int tid = threadIdx.x, wave = tid >> 6, lane = tid & 63;
    const int grp = lane >> 4, l16 = lane & 15;

    const size_t qkbase = (size_t)(b * SS) * 2048 + h * DHH;
    const size_t vbase  = (size_t)((b * HH + h) * 64) * 2048;
    const float SC = 0.18033688f;          // 0.125 * log2(e)
    const float MNEG = -1.442695e9f;       // -1e9 * log2(e)

    // ---- stage Q (once) ----
#pragma unroll
    for (int it = 0; it < 2; ++it) {
        const int slot = it * 512 + tid;
        const int row = slot >> 3, dhb = slot & 7;
        const int src = (dhb ^ ((row + (row >> 3)) & 7)) * 8;
        gld16(&qk[qkbase + (size_t)(q0 + row) * 2048 + src],
              &Qs[it * 4096 + wave * 512]);
    }
    const int krow = tid >> 3, kdhb = tid & 7;
    const int ksrc = (kdhb ^ ((krow + (krow >> 3)) & 7)) * 8;

    // ---- stage tile 0 ----
    gld16(&qk[qkbase + (size_t)krow * 2048 + 1024 + ksrc], &Ks[0][wave * 512]);
    gld16(&vt[vbase + (size_t)krow * 2048 + ksrc],         &Vs[0][wave * 512]);
    if (tid < 64) maskf[0][tid] = mask[b * SS + tid] ? 0.f : MNEG;
    __syncthreads();

    const s16x8 aq0 = *(const s16x8*)&Qs[sidx(wave * 16 + l16, grp * 8)];
    const s16x8 aq1 = *(const s16x8*)&Qs[sidx(wave * 16 + l16, 32 + grp * 8)];
    const s16x8 ones = {(short)0x3F80, (short)0x3F80, (short)0x3F80, (short)0x3F80,
                        (short)0x3F80, (short)0x3F80, (short)0x3F80, (short)0x3F80};

    f32x4 accO[4];
#pragma unroll
    for (int j = 0; j < 4; ++j) accO[j] = (f32x4){0.f, 0.f, 0.f, 0.f};
    f32x4 accS = (f32x4){0.f, 0.f, 0.f, 0.f};
    float mrow[4] = {-1e30f, -1e30f, -1e30f, -1e30f};

    for (int kt = 0; kt < SS / 64; ++kt) {
        const int cur = kt & 1;
        // prefetch next tile into the other buffer
        if (kt + 1 < SS / 64) {
            const int kv1 = (kt + 1) * 64;
            gld16(&qk[qkbase + (size_t)(kv1 + krow) * 2048 + 1024 + ksrc],
                  &Ks[cur ^ 1][wave * 512]);
            gld16(&vt[vbase + (size_t)krow * 2048 + kv1 + ksrc],
                  &Vs[cur ^ 1][wave * 512]);
            if (tid < 64) maskf[cur ^ 1][tid] = mask[b * SS + kv1 + tid] ? 0.f : MNEG;
        }
        float madd[4];
#pragma unroll
        for (int j = 0; j < 4; ++j) madd[j] = maskf[cur][j * 16 + l16];

        // ---- QK^T ----
        f32x4 sv[4];
        __builtin_amdgcn_s_setprio(1);
#pragma unroll
        for (int j = 0; j < 4; ++j) {
            const s16x8 bk0 = *(const s16x8*)&Ks[cur][sidx(j * 16 + l16, grp * 8)];
            const s16x8 bk1 = *(const s16x8*)&Ks[cur][sidx(j * 16 + l16, 32 + grp * 8)];
            f32x4 z = (f32x4){0.f, 0.f, 0.f, 0.f};
            z = __builtin_amdgcn_mfma_f32_16x16x32_bf16(aq0, bk0, z, 0, 0, 0);
            z = __builtin_amdgcn_mfma_f32_16x16x32_bf16(aq1, bk1, z, 0, 0, 0);
            sv[j] = z;
        }
        __builtin_amdgcn_s_setprio(0);
#pragma unroll
        for (int j = 0; j < 4; ++j)
#pragma unroll
            for (int r = 0; r < 4; ++r)
                sv[j][r] = sv[j][r] * SC + madd[j];

        // ---- online softmax: defer-max + P write ----
#pragma unroll
        for (int r = 0; r < 4; ++r) {
            float mx = fmaxf(fmaxf(sv[0][r], sv[1][r]), fmaxf(sv[2][r], sv[3][r]));
#pragma unroll
            for (int off = 1; off < 16; off <<= 1)
                mx = fmaxf(mx, __shfl_xor(mx, off));
            if (!__all(mx <= mrow[r] + 8.f)) {
                const float mnew = fmaxf(mrow[r], mx);
                const float corr = __builtin_amdgcn_exp2f(mrow[r] - mnew);
                mrow[r] = mnew;
#pragma unroll
                for (int j = 0; j < 4; ++j) accO[j][r] *= corr;
                accS[r] *= corr;
            }
            const int prow = wave * 16 + grp * 4 + r;
#pragma unroll
            for (int j = 0; j < 4; ++j) {
                const float p = __builtin_amdgcn_exp2f(sv[j][r] - mrow[r]);
                Ps[wave * 1024 + sidx(grp * 4 + r, l16 + 16 * j)] = f2b(p);
            }
            (void)prow;
        }

        // ---- PV + MFMA row-sum (wave-private P strip) ----
        const s16x8 pa0 = *(const s16x8*)&Ps[wave * 1024 + sidx(l16, grp * 8)];
        const s16x8 pa1 = *(const s16x8*)&Ps[wave * 1024 + sidx(l16, 32 + grp * 8)];
        __builtin_amdgcn_s_setprio(1);
        accS = __builtin_amdgcn_mfma_f32_16x16x32_bf16(pa0, ones, accS, 0, 0, 0);
        accS = __builtin_amdgcn_mfma_f32_16x16x32_bf16(pa1, ones, accS, 0, 0, 0);
#pragma unroll
        for (int j = 0; j < 4; ++j) {
            const s16x8 vb0 = *(const s16x8*)&Vs[cur][sidx(j * 16 + l16, grp * 8)];
            const s16x8 vb1 = *(const s16x8*)&Vs[cur][sidx(j * 16 + l16, 32 + grp * 8)];
            accO[j] = __builtin_amdgcn_mfma_f32_16x16x32_bf16(pa0, vb0, accO[j], 0, 0, 0);
            accO[j] = __builtin_amdgcn_mfma_f32_16x16x32_bf16(pa1, vb1, accO[j], 0, 0, 0);
        }
        __builtin_amdgcn_s_setprio(0);
        __syncthreads();   // next-tile staging landed; this tile's reads done
    }

    // ---- epilogue ----
#pragma unroll
    for (int r = 0; r < 4; ++r) {
        const float inv = 1.0f / accS[r];
        const int row = q0 + wave * 16 + grp * 4 + r;
#pragma unroll
        for (int j = 0; j < 4; ++j)
            o[(size_t)(b * SS + row) * DD + h * DHH + j * 16 + l16] =
                f2b(accO[j][r] * inv);
    }
}

// ---------------------------------------------------------------------------
template <int OUTBF>
__global__ __launch_bounds__(256)
void ln_kernel(const float* __restrict__ x, const float* __restrict__ g,
               const float* __restrict__ beta, void* __restrict__ outv)
{
    const int row = blockIdx.x;
    const int tid = threadIdx.x;
    const float4 xl = reinterpret_cast<const float4*>(x + (size_t)row * DD)[tid];
    float s  = xl.x + xl.y + xl.z + xl.w;
    float sq = xl.x * xl.x + xl.y * xl.y + xl.z * xl.z + xl.w * xl.w;
#pragma unroll
    for (int off = 1; off < 64; off <<= 1) {
        s  += __shfl_xor(s, off);
        sq += __shfl_xor(sq, off);
    }
    __shared__ float ssum[4], ssq[4];
    const int wid = tid >> 6;
    if ((tid & 63) == 0) { ssum[wid] = s; ssq[wid] = sq; }
    __syncthreads();
    s  = ssum[0] + ssum[1] + ssum[2] + ssum[3];
    sq = ssq[0]  + ssq[1]  + ssq[2]  + ssq[3];
    const float mean = s * (1.0f / DD);
    const float var  = fmaxf(sq * (1.0f / DD) - mean * mean, 0.0f);
    const float rstd = rsqrtf(var + 1e-5f);
    const float4 gv = reinterpret_cast<const float4*>(g)[tid];
    const float4 bv = reinterpret_cast<const float4*>(beta)[tid];
    float4 ov;
    ov.x = (xl.x - mean) * rstd * gv.x + bv.x;
    ov.y = (xl.y - mean) * rstd * gv.y + bv.y;
    ov.z = (xl.z - mean) * rstd * gv.z + bv.z;
    ov.w = (xl.w - mean) * rstd * gv.w + bv.w;
    if (OUTBF) {
        ushort4 o4;
        o4.x = f2b(ov.x); o4.y = f2b(ov.y); o4.z = f2b(ov.z); o4.w = f2b(ov.w);
        reinterpret_cast<ushort4*>(outv)[(size_t)row * 256 + tid] = o4;
    } else {
        reinterpret_cast<float4*>(outv)[(size_t)row * 256 + tid] = ov;
    }
}

// ---------------------------------------------------------------------------
extern "C" void kernel_launch(void* const* d_in, const int* in_sizes, int n_in,
                              void* d_out, int out_size, void* d_ws, size_t ws_size,
                              hipStream_t stream)
{
    (void)in_sizes; (void)n_in; (void)out_size; (void)ws_size;

    const float* x     = (const float*)d_in[0];
    const int*   mask  = (const int*)  d_in[1];
    const float* wq    = (const float*)d_in[2];
    const float* bq    = (const float*)d_in[3];
    const float* wk    = (const float*)d_in[4];
    const float* bk    = (const float*)d_in[5];
    const float* wv    = (const float*)d_in[6];
    const float* bv    = (const float*)d_in[7];
    const float* wo    = (const float*)d_in[8];
    const float* bo    = (const float*)d_in[9];
    const float* ln1_g = (const float*)d_in[10];
    const float* ln1_b = (const float*)d_in[11];
    const float* w1    = (const float*)d_in[12];
    const float* b1    = (const float*)d_in[13];
    const float* w2    = (const float*)d_in[14];
    const float* b2    = (const float*)d_in[15];
    const float* ln2_g = (const float*)d_in[16];
    const float* ln2_b = (const float*)d_in[17];

    float* out = (float*)d_out;
    char*  wsb = (char*)d_ws;
    const size_t MB = 1u << 20;

    unsigned short* wqkvT = (unsigned short*)(wsb + 0);        // [3072][1024]
    unsigned short* woT   = (unsigned short*)(wsb + 6 * MB);   // [1024][1024]
    unsigned short* w1T   = (unsigned short*)(wsb + 8 * MB);   // [2048][1024]
    unsigned short* w2T   = (unsigned short*)(wsb + 12 * MB);  // [1024][2048]
    float*          bqkv  = (float*)(wsb + 16 * MB);           // [3072]
    unsigned short* qkb   = (unsigned short*)(wsb + 17 * MB);  // [4096][2048]
    unsigned short* vtb   = (unsigned short*)(wsb + 33 * MB);  // [2*16*64][2048]
    unsigned short* xb    = (unsigned short*)(wsb + 41 * MB);  // [4096][1024]
    unsigned short* ab16  = xb;                                // attn out reuses xb
    float*          t0    = (float*)(wsb + 17 * MB);           // qkb dead
    unsigned short* hb16  = (unsigned short*)(wsb + 33 * MB);  // vtb dead
    unsigned short* f1b   = (unsigned short*)(wsb + 41 * MB);  // [4096][2048]
    float*          t1    = (float*)(wsb + 17 * MB);           // t0 dead

    // fused prep: x->bf16, 6 transposes, bias pack
    prep<<<6156, 256, 0, stream>>>(x, wq, wk, wv, wo, w1, w2, bq, bk, bv,
                                   xb, wqkvT, woT, w1T, w2T, bqkv);
    // fused QKV projection: q|k -> qkb, v -> vtb transposed per head
    mgemm<0, 0, 0, 1><<<dim3(24, 32), 256, 0, stream>>>(
        xb, wqkvT, bqkv, nullptr, qkb, vtb, MM, 3 * DD, DD, 2048);
    // flash attention
    attn_mfma<<<dim3(SS / 128, HH, BB), 512, 0, stream>>>(qkb, vtb, mask, ab16);
    // output projection + residual x
    mgemm<0, 1, 1, 0><<<dim3(8, 32), 256, 0, stream>>>(
        ab16, woT, bo, x, t0, nullptr, MM, DD, DD, DD);
    // LN1 -> bf16
    ln_kernel<1><<<MM, 256, 0, stream>>>(t0, ln1_g, ln1_b, hb16);
    // FFN
    mgemm<1, 0, 0, 0><<<dim3(16, 32), 256, 0, stream>>>(
        hb16, w1T, b1, nullptr, f1b, nullptr, MM, 2 * DD, DD, 2 * DD);
    mgemm<0, 2, 1, 0><<<dim3(8, 32), 256, 0, stream>>>(
        f1b, w2T, b2, hb16, t1, nullptr, MM, DD, 2 * DD, DD);
    // LN2 -> out
    ln_kernel<0><<<MM, 256, 0, stream>>>(t1, ln2_g, ln2_b, out);
}

// Round 7
// 242.653 us; speedup vs baseline: 7.7125x; 1.2300x over previous
//
#include <hip/hip_runtime.h>
#include <math.h>

#define BB  2
#define SS  2048
#define DD  1024
#define HH  16
#define DHH 64
#define MM  (BB * SS)   // 4096 rows

typedef float f32x4 __attribute__((ext_vector_type(4)));
typedef short s16x8 __attribute__((ext_vector_type(8)));

__device__ __forceinline__ unsigned short f2b(float f) {
    union { float f; unsigned u; } v; v.f = f;
    unsigned r = v.u + 0x7fffu + ((v.u >> 16) & 1u);
    return (unsigned short)(r >> 16);
}
__device__ __forceinline__ float b2f(unsigned short u) {
    union { unsigned u; float f; } v; v.u = ((unsigned)u) << 16;
    return v.f;
}
// pack 2 f32 -> 2 bf16 (low=first), RNE
__device__ __forceinline__ unsigned cvtpk(float lo, float hi) {
    unsigned r;
    asm("v_cvt_pk_bf16_f32 %0, %1, %2" : "=v"(r) : "v"(lo), "v"(hi));
    return r;
}

typedef __attribute__((address_space(1))) void gv_t;
typedef __attribute__((address_space(3))) void lv_t;
__device__ __forceinline__ void gld16(const void* g, void* l) {
    __builtin_amdgcn_global_load_lds((gv_t*)(void*)g, (lv_t*)l, 16, 0, 0);
}

// LDS swizzle for 64-col bf16 tiles: XOR sigma(row)=(row+row>>3)&7 on 16B-block bits.
__device__ __forceinline__ int sidx(int row, int col) {
    return row * 64 + (col ^ (((row + (row >> 3)) & 7) << 3));
}

// ---------------------------------------------------------------------------
// bf16 MFMA GEMM (m97 structure): C[M,N] = A[M,K] @ B^T[N,K] + bias (+res)(relu)
// VS=1: QKV mode — cols<2048 -> out (stride outN), cols>=2048 -> vt transposed
// per head: vt[b][h][dh][s].
// ---------------------------------------------------------------------------
template <int RELU, int RES, int OUTF, int VS>
__global__ __launch_bounds__(256)
void mgemm(const unsigned short* __restrict__ A, const unsigned short* __restrict__ B,
           const float* __restrict__ bias, const void* __restrict__ res,
           void* __restrict__ out, unsigned short* __restrict__ vt,
           int M, int N, int K, int outN)
{
    __shared__ short As[128 * 64];
    __shared__ short Bs[128 * 64];

    const int tid  = threadIdx.x;
    const int wave = tid >> 6, lane = tid & 63;
    const int bm = blockIdx.y * 128, bn = blockIdx.x * 128;
    const int srow = tid >> 3;
    const int scol = (tid & 7) * 8;
    const int wr = wave >> 1, wc = wave & 1;
    const int fr = lane & 15;
    const int fk = (lane >> 4) * 8;

    f32x4 acc[4][4];
#pragma unroll
    for (int i = 0; i < 4; ++i)
#pragma unroll
        for (int j = 0; j < 4; ++j) acc[i][j] = (f32x4){0.f, 0.f, 0.f, 0.f};

    for (int k0 = 0; k0 < K; k0 += 64) {
#pragma unroll
        for (int it = 0; it < 4; ++it) {
            gld16(&A[(size_t)(bm + it * 32 + srow) * K + k0 + scol],
                  &As[it * 2048 + wave * 512]);
            gld16(&B[(size_t)(bn + it * 32 + srow) * K + k0 + scol],
                  &Bs[it * 2048 + wave * 512]);
        }
        __syncthreads();

#pragma unroll
        for (int kk = 0; kk < 2; ++kk) {
            s16x8 af[4], bf[4];
#pragma unroll
            for (int i = 0; i < 4; ++i)
                af[i] = *(const s16x8*)&As[(wr * 64 + i * 16 + fr) * 64 + kk * 32 + fk];
#pragma unroll
            for (int j = 0; j < 4; ++j)
                bf[j] = *(const s16x8*)&Bs[(wc * 64 + j * 16 + fr) * 64 + kk * 32 + fk];
#pragma unroll
            for (int i = 0; i < 4; ++i)
#pragma unroll
                for (int j = 0; j < 4; ++j)
                    acc[i][j] = __builtin_amdgcn_mfma_f32_16x16x32_bf16(
                        af[i], bf[j], acc[i][j], 0, 0, 0);
        }
        __syncthreads();
    }

    const int r0 = bm + wr * 64 + (lane >> 4) * 4;
    const int c0 = bn + wc * 64 + (lane & 15);
    const float* resf          = (const float*)res;
    const unsigned short* resh = (const unsigned short*)res;
    float* outf          = (float*)out;
    unsigned short* outh = (unsigned short*)out;

    if (VS == 1 && bn >= 2048) {
#pragma unroll
        for (int i = 0; i < 4; ++i)
#pragma unroll
            for (int j = 0; j < 4; ++j) {
                const int col = c0 + j * 16;
                const int hh = (col >> 6) & 15, dh = col & 63;
                const float bcol = bias[col];
#pragma unroll
                for (int r = 0; r < 4; ++r) {
                    const int row = r0 + i * 16 + r;
                    const int bb = row >> 11, s = row & 2047;
                    vt[(size_t)(((bb * 16 + hh) * 64) + dh) * 2048 + s] =
                        f2b(acc[i][j][r] + bcol);
                }
            }
        return;
    }

#pragma unroll
    for (int i = 0; i < 4; ++i)
#pragma unroll
        for (int j = 0; j < 4; ++j) {
            const int col = c0 + j * 16;
            const float bcol = bias[col];
#pragma unroll
            for (int r = 0; r < 4; ++r) {
                const int row = r0 + i * 16 + r;
                float v = acc[i][j][r] + bcol;
                if (RES == 1) v += resf[(size_t)row * outN + col];
                if (RES == 2) v += b2f(resh[(size_t)row * outN + col]);
                if (RELU)     v = fmaxf(v, 0.f);
                if (OUTF) outf[(size_t)row * outN + col] = v;
                else      outh[(size_t)row * outN + col] = f2b(v);
            }
        }
}

// ---------------------------------------------------------------------------
// Fused prep: x->bf16, 6 weight transposes (fp32[K][N] -> bf16[N][K]), bias pack.
// ---------------------------------------------------------------------------
__global__ __launch_bounds__(256)
void prep(const float* __restrict__ x,
          const float* __restrict__ wq, const float* __restrict__ wk,
          const float* __restrict__ wv, const float* __restrict__ wo,
          const float* __restrict__ w1, const float* __restrict__ w2,
          const float* __restrict__ bq, const float* __restrict__ bk,
          const float* __restrict__ bv,
          unsigned short* __restrict__ xb, unsigned short* __restrict__ wqkvT,
          unsigned short* __restrict__ woT, unsigned short* __restrict__ w1T,
          unsigned short* __restrict__ w2T, float* __restrict__ bqkv)
{
    __shared__ float T[64][65];
    const int tid = threadIdx.x;
    int bid = blockIdx.x;

    if (bid < 4096) {   // x -> bf16
        const int i = bid * 256 + tid;
        const float4 v = ((const float4*)x)[i];
        ushort4 o4;
        o4.x = f2b(v.x); o4.y = f2b(v.y); o4.z = f2b(v.z); o4.w = f2b(v.w);
        ((ushort4*)xb)[i] = o4;
        return;
    }
    bid -= 4096;

    if (bid >= 2048) {  // bias pack, 12 blocks
        const int i = (bid - 2048) * 256 + tid;
        if (i < 1024) bqkv[i] = bq[i];
        else if (i < 2048) bqkv[i] = bk[i - 1024];
        else if (i < 3072) bqkv[i] = bv[i - 2048];
        return;
    }

    const float* src; unsigned short* dst; int K, N, nbx, sub;
    if (bid < 256)       { src = wq; dst = wqkvT;               K = 1024; N = 1024; nbx = 16; sub = bid; }
    else if (bid < 512)  { src = wk; dst = wqkvT + 1024 * 1024; K = 1024; N = 1024; nbx = 16; sub = bid - 256; }
    else if (bid < 768)  { src = wv; dst = wqkvT + 2048 * 1024; K = 1024; N = 1024; nbx = 16; sub = bid - 512; }
    else if (bid < 1024) { src = wo; dst = woT;                 K = 1024; N = 1024; nbx = 16; sub = bid - 768; }
    else if (bid < 1536) { src = w1; dst = w1T;                 K = 1024; N = 2048; nbx = 32; sub = bid - 1024; }
    else                 { src = w2; dst = w2T;                 K = 2048; N = 1024; nbx = 16; sub = bid - 1536; }

    const int n0 = (sub % nbx) * 64, k0 = (sub / nbx) * 64;
    const int c = tid & 63, rb = tid >> 6;
#pragma unroll
    for (int it = 0; it < 16; ++it) {
        const int r = it * 4 + rb;
        T[r][c] = src[(size_t)(k0 + r) * N + n0 + c];
    }
    __syncthreads();
#pragma unroll
    for (int it = 0; it < 16; ++it) {
        const int r = it * 4 + rb;
        dst[(size_t)(n0 + r) * K + k0 + c] = f2b(T[c][r]);
    }
}

// ---------------------------------------------------------------------------
// MFMA flash attention v5 (swapped QK^T). qk: [B*S][2048] = [q|k];
// vt: [B][H][64][2048]. Block = 128 q-rows x head x batch, 8 waves.
// Swapped QK^T: z = mfma(K_frag, Q_frag) -> lane holds S[q=l16][k=j*16+grp*4+r]
// => lane-local row max + 2 shfl. P packed via v_cvt_pk_bf16_f32 into the dead
// Q buffer (wave-private strip). PV / accS(ones) / epilogue = verified paths.
// ---------------------------------------------------------------------------
__global__ __launch_bounds__(512)
void attn_mfma(const unsigned short* __restrict__ qk,
               const unsigned short* __restrict__ vt,
               const int* __restrict__ mask, unsigned short* __restrict__ o)
{
    const int b = blockIdx.z, h = blockIdx.y, q0 = blockIdx.x * 128;
    __shared__ unsigned short QP[8192];   // 128x64 Q; after frag load: P strips
    __shared__ unsigned short Ks[4096];   // 64x64
    __shared__ unsigned short Vs[4096];   // 64x64 (rows=dh, cols=kv)
    __shared__ float maskf[64];
    const int tid = threadIdx.x, wave = tid >> 6, lane = tid & 63;
    const int grp = lane >> 4, l16 = lane & 15;

    const size_t qkbase = (size_t)(b * SS) * 2048 + h * DHH;
    const size_t vbase  = (size_t)((b * HH + h) * 64) * 2048;
    const float SC = 0.18033688f;          // 0.125 * log2(e)
    const float MNEG = -1.442695e9f;       // -1e9 * log2(e)

    // ---- stage Q (once) ----
#pragma unroll
    for (int it = 0; it < 2; ++it) {
        const int slot = it * 512 + tid;
        const int row = slot >> 3, dhb = slot & 7;
        const int src = (dhb ^ ((row + (row >> 3)) & 7)) * 8;
        gld16(&qk[qkbase + (size_t)(q0 + row) * 2048 + src],
              &QP[it * 4096 + wave * 512]);
    }
    const int krow = tid >> 3, kdhb = tid & 7;
    const int ksrc = (kdhb ^ ((krow + (krow >> 3)) & 7)) * 8;
    __syncthreads();
    const int prow = wave * 16 + l16;     // this lane's q row (LDS row index)
    const s16x8 aq0 = *(const s16x8*)&QP[sidx(prow, grp * 8)];
    const s16x8 aq1 = *(const s16x8*)&QP[sidx(prow, 32 + grp * 8)];
    // QP strip [wave*1024 ..) is now reused for P (wave-local, lgkm-ordered)

    const s16x8 ones = {(short)0x3F80, (short)0x3F80, (short)0x3F80, (short)0x3F80,
                        (short)0x3F80, (short)0x3F80, (short)0x3F80, (short)0x3F80};

    f32x4 accO[4];
#pragma unroll
    for (int j = 0; j < 4; ++j) accO[j] = (f32x4){0.f, 0.f, 0.f, 0.f};
    f32x4 accS = (f32x4){0.f, 0.f, 0.f, 0.f};
    float mrow = -1e30f;                   // running max for q = l16 (scalar)

    for (int kt = 0; kt < SS / 64; ++kt) {
        const int kv0 = kt * 64;
        __syncthreads();   // prev tile reads done
        gld16(&qk[qkbase + (size_t)(kv0 + krow) * 2048 + 1024 + ksrc], &Ks[wave * 512]);
        gld16(&vt[vbase + (size_t)krow * 2048 + kv0 + ksrc],           &Vs[wave * 512]);
        if (tid < 64) maskf[tid] = mask[b * SS + kv0 + tid] ? 0.f : MNEG;
        __syncthreads();   // staging + maskf visible

        // ---- QK^T (swapped: K is A, Q is B) ----
        f32x4 sv[4];
        __builtin_amdgcn_s_setprio(1);
#pragma unroll
        for (int j = 0; j < 4; ++j) {
            const s16x8 bk0 = *(const s16x8*)&Ks[sidx(j * 16 + l16, grp * 8)];
            const s16x8 bk1 = *(const s16x8*)&Ks[sidx(j * 16 + l16, 32 + grp * 8)];
            f32x4 z = (f32x4){0.f, 0.f, 0.f, 0.f};
            z = __builtin_amdgcn_mfma_f32_16x16x32_bf16(bk0, aq0, z, 0, 0, 0);
            z = __builtin_amdgcn_mfma_f32_16x16x32_bf16(bk1, aq1, z, 0, 0, 0);
            sv[j] = z;   // sv[j][r] = S[q=l16][k = j*16 + grp*4 + r]
        }
        __builtin_amdgcn_s_setprio(0);
#pragma unroll
        for (int j = 0; j < 4; ++j) {
            const float4 mv = *(const float4*)&maskf[j * 16 + grp * 4];
            sv[j][0] = sv[j][0] * SC + mv.x;
            sv[j][1] = sv[j][1] * SC + mv.y;
            sv[j][2] = sv[j][2] * SC + mv.z;
            sv[j][3] = sv[j][3] * SC + mv.w;
        }

        // ---- softmax for q=l16: lane-local max + 2 shfl ----
        float mx = -1e30f;
#pragma unroll
        for (int j = 0; j < 4; ++j)
#pragma unroll
            for (int r = 0; r < 4; ++r) mx = fmaxf(mx, sv[j][r]);
        mx = fmaxf(mx, __shfl_xor(mx, 16));
        mx = fmaxf(mx, __shfl_xor(mx, 32));

        if (!__all(mx <= mrow + 8.f)) {
            const float mnew = fmaxf(mrow, mx);
            const float corrq = __builtin_amdgcn_exp2f(mrow - mnew);  // for q=l16
            mrow = mnew;
            float cr[4];   // corr for q = grp*4+r (PV accumulator layout)
#pragma unroll
            for (int r = 0; r < 4; ++r) cr[r] = __shfl(corrq, grp * 4 + r);
#pragma unroll
            for (int r = 0; r < 4; ++r) {
                accS[r] *= cr[r];
#pragma unroll
                for (int j = 0; j < 4; ++j) accO[j][r] *= cr[r];
            }
        }

        // ---- P = exp2, pack to bf16, write wave-private strip ----
#pragma unroll
        for (int j = 0; j < 4; ++j) {
            const float p0 = __builtin_amdgcn_exp2f(sv[j][0] - mrow);
            const float p1 = __builtin_amdgcn_exp2f(sv[j][1] - mrow);
            const float p2 = __builtin_amdgcn_exp2f(sv[j][2] - mrow);
            const float p3 = __builtin_amdgcn_exp2f(sv[j][3] - mrow);
            *(unsigned*)&QP[sidx(prow, j * 16 + grp * 4)]     = cvtpk(p0, p1);
            *(unsigned*)&QP[sidx(prow, j * 16 + grp * 4 + 2)] = cvtpk(p2, p3);
        }

        // ---- PV + ones row-sum ----
        const s16x8 pa0 = *(const s16x8*)&QP[sidx(prow, grp * 8)];
        const s16x8 pa1 = *(const s16x8*)&QP[sidx(prow, 32 + grp * 8)];
        __builtin_amdgcn_s_setprio(1);
        accS = __builtin_amdgcn_mfma_f32_16x16x32_bf16(pa0, ones, accS, 0, 0, 0);
        accS = __builtin_amdgcn_mfma_f32_16x16x32_bf16(pa1, ones, accS, 0, 0, 0);
#pragma unroll
        for (int j = 0; j < 4; ++j) {
            const s16x8 vb0 = *(const s16x8*)&Vs[sidx(j * 16 + l16, grp * 8)];
            const s16x8 vb1 = *(const s16x8*)&Vs[sidx(j * 16 + l16, 32 + grp * 8)];
            accO[j] = __builtin_amdgcn_mfma_f32_16x16x32_bf16(pa0, vb0, accO[j], 0, 0, 0);
            accO[j] = __builtin_amdgcn_mfma_f32_16x16x32_bf16(pa1, vb1, accO[j], 0, 0, 0);
        }
        __builtin_amdgcn_s_setprio(0);
    }

    // ---- epilogue (accO/accS rows: q = grp*4+r; cols: dh = j*16+l16) ----
#pragma unroll
    for (int r = 0; r < 4; ++r) {
        const float inv = 1.0f / accS[r];
        const int row = q0 + wave * 16 + grp * 4 + r;
#pragma unroll
        for (int j = 0; j < 4; ++j)
            o[(size_t)(b * SS + row) * DD + h * DHH + j * 16 + l16] =
                f2b(accO[j][r] * inv);
    }
}

// ---------------------------------------------------------------------------
template <int OUTBF>
__global__ __launch_bounds__(256)
void ln_kernel(const float* __restrict__ x, const float* __restrict__ g,
               const float* __restrict__ beta, void* __restrict__ outv)
{
    const int row = blockIdx.x;
    const int tid = threadIdx.x;
    const float4 xl = reinterpret_cast<const float4*>(x + (size_t)row * DD)[tid];
    float s  = xl.x + xl.y + xl.z + xl.w;
    float sq = xl.x * xl.x + xl.y * xl.y + xl.z * xl.z + xl.w * xl.w;
#pragma unroll
    for (int off = 1; off < 64; off <<= 1) {
        s  += __shfl_xor(s, off);
        sq += __shfl_xor(sq, off);
    }
    __shared__ float ssum[4], ssq[4];
    const int wid = tid >> 6;
    if ((tid & 63) == 0) { ssum[wid] = s; ssq[wid] = sq; }
    __syncthreads();
    s  = ssum[0] + ssum[1] + ssum[2] + ssum[3];
    sq = ssq[0]  + ssq[1]  + ssq[2]  + ssq[3];
    const float mean = s * (1.0f / DD);
    const float var  = fmaxf(sq * (1.0f / DD) - mean * mean, 0.0f);
    const float rstd = rsqrtf(var + 1e-5f);
    const float4 gv = reinterpret_cast<const float4*>(g)[tid];
    const float4 bv = reinterpret_cast<const float4*>(beta)[tid];
    float4 ov;
    ov.x = (xl.x - mean) * rstd * gv.x + bv.x;
    ov.y = (xl.y - mean) * rstd * gv.y + bv.y;
    ov.z = (xl.z - mean) * rstd * gv.z + bv.z;
    ov.w = (xl.w - mean) * rstd * gv.w + bv.w;
    if (OUTBF) {
        ushort4 o4;
        o4.x = f2b(ov.x); o4.y = f2b(ov.y); o4.z = f2b(ov.z); o4.w = f2b(ov.w);
        reinterpret_cast<ushort4*>(outv)[(size_t)row * 256 + tid] = o4;
    } else {
        reinterpret_cast<float4*>(outv)[(size_t)row * 256 + tid] = ov;
    }
}

// ---------------------------------------------------------------------------
extern "C" void kernel_launch(void* const* d_in, const int* in_sizes, int n_in,
                              void* d_out, int out_size, void* d_ws, size_t ws_size,
                              hipStream_t stream)
{
    (void)in_sizes; (void)n_in; (void)out_size; (void)ws_size;

    const float* x     = (const float*)d_in[0];
    const int*   mask  = (const int*)  d_in[1];
    const float* wq    = (const float*)d_in[2];
    const float* bq    = (const float*)d_in[3];
    const float* wk    = (const float*)d_in[4];
    const float* bk    = (const float*)d_in[5];
    const float* wv    = (const float*)d_in[6];
    const float* bv    = (const float*)d_in[7];
    const float* wo    = (const float*)d_in[8];
    const float* bo    = (const float*)d_in[9];
    const float* ln1_g = (const float*)d_in[10];
    const float* ln1_b = (const float*)d_in[11];
    const float* w1    = (const float*)d_in[12];
    const float* b1    = (const float*)d_in[13];
    const float* w2    = (const float*)d_in[14];
    const float* b2    = (const float*)d_in[15];
    const float* ln2_g = (const float*)d_in[16];
    const float* ln2_b = (const float*)d_in[17];

    float* out = (float*)d_out;
    char*  wsb = (char*)d_ws;
    const size_t MB = 1u << 20;

    unsigned short* wqkvT = (unsigned short*)(wsb + 0);        // [3072][1024]
    unsigned short* woT   = (unsigned short*)(wsb + 6 * MB);   // [1024][1024]
    unsigned short* w1T   = (unsigned short*)(wsb + 8 * MB);   // [2048][1024]
    unsigned short* w2T   = (unsigned short*)(wsb + 12 * MB);  // [1024][2048]
    float*          bqkv  = (float*)(wsb + 16 * MB);           // [3072]
    unsigned short* qkb   = (unsigned short*)(wsb + 17 * MB);  // [4096][2048]
    unsigned short* vtb   = (unsigned short*)(wsb + 33 * MB);  // [2*16*64][2048]
    unsigned short* xb    = (unsigned short*)(wsb + 41 * MB);  // [4096][1024]
    unsigned short* ab16  = xb;                                // attn out reuses xb
    float*          t0    = (float*)(wsb + 17 * MB);           // qkb dead
    unsigned short* hb16  = (unsigned short*)(wsb + 33 * MB);  // vtb dead
    unsigned short* f1b   = (unsigned short*)(wsb + 41 * MB);  // [4096][2048]
    float*          t1    = (float*)(wsb + 17 * MB);           // t0 dead

    // fused prep: x->bf16, 6 transposes, bias pack
    prep<<<6156, 256, 0, stream>>>(x, wq, wk, wv, wo, w1, w2, bq, bk, bv,
                                   xb, wqkvT, woT, w1T, w2T, bqkv);
    // fused QKV projection: q|k -> qkb, v -> vtb transposed per head
    mgemm<0, 0, 0, 1><<<dim3(24, 32), 256, 0, stream>>>(
        xb, wqkvT, bqkv, nullptr, qkb, vtb, MM, 3 * DD, DD, 2048);
    // flash attention
    attn_mfma<<<dim3(SS / 128, HH, BB), 512, 0, stream>>>(qkb, vtb, mask, ab16);
    // output projection + residual x
    mgemm<0, 1, 1, 0><<<dim3(8, 32), 256, 0, stream>>>(
        ab16, woT, bo, x, t0, nullptr, MM, DD, DD, DD);
    // LN1 -> bf16
    ln_kernel<1><<<MM, 256, 0, stream>>>(t0, ln1_g, ln1_b, hb16);
    // FFN
    mgemm<1, 0, 0, 0><<<dim3(16, 32), 256, 0, stream>>>(
        hb16, w1T, b1, nullptr, f1b, nullptr, MM, 2 * DD, DD, 2 * DD);
    mgemm<0, 2, 1, 0><<<dim3(8, 32), 256, 0, stream>>>(
        f1b, w2T, b2, hb16, t1, nullptr, MM, DD, 2 * DD, DD);
    // LN2 -> out
    ln_kernel<0><<<MM, 256, 0, stream>>>(t1, ln2_g, ln2_b, out);
}